// Round 2
// baseline (2642.836 us; speedup 1.0000x reference)
//
#include <hip/hip_runtime.h>
#include <cstdint>

#define EPSF 1e-5f

// workspace layout (float offsets)
#define WS_MS 0        // M_s  [k=84][o=64]
#define WS_MT 5376     // M_t  [k=84][o=64]
#define WS_B0 10752    // bias0 [64]  (folded ps-BN bias)
#define WS_WC 10816    // conv w folded [i=9][o=64]
#define WS_BC 11392    // conv bias folded [64]
#define WS_WF 11456    // W_fu folded [c=128][o=64]
#define WS_BF 19648    // fu bias folded [64]
#define WS_TOTAL 19712

__global__ __launch_bounds__(64) void stem_prep(
    const float* __restrict__ W_ssig, const float* __restrict__ b_ssig,
    const float* __restrict__ W_tsig, const float* __restrict__ b_tsig,
    const float* __restrict__ W_raw,  const float* __restrict__ b_raw,
    const float* __restrict__ W_ps,   const float* __restrict__ b_ps,
    const float* __restrict__ W_fu,   const float* __restrict__ b_fu,
    const float* __restrict__ g_raw, const float* __restrict__ be_raw,
    const float* __restrict__ m_raw, const float* __restrict__ v_raw,
    const float* __restrict__ g_ps,  const float* __restrict__ be_ps,
    const float* __restrict__ m_ps,  const float* __restrict__ v_ps,
    const float* __restrict__ g_fu,  const float* __restrict__ be_fu,
    const float* __restrict__ m_fu,  const float* __restrict__ v_fu,
    float* __restrict__ ws)
{
    const int o = threadIdx.x;        // 0..63 output channel
    const int bid = blockIdx.x;
    if (bid < 84) {
        const int k = bid;
        const float sps = g_ps[o] / sqrtf(v_ps[o] + EPSF);
        float accs = 0.f, acct = 0.f;
        for (int c = 0; c < 64; ++c) {
            accs = fmaf(W_ps[o*128 + c],      W_ssig[c*84 + k], accs);
            acct = fmaf(W_ps[o*128 + 64 + c], W_tsig[c*84 + k], acct);
        }
        ws[WS_MS + k*64 + o] = accs * sps;
        ws[WS_MT + k*64 + o] = acct * sps;
    } else if (bid == 84) {
        const float sps = g_ps[o] / sqrtf(v_ps[o] + EPSF);
        float acc = b_ps[o] - m_ps[o];
        for (int c = 0; c < 64; ++c) {
            acc = fmaf(W_ps[o*128 + c],      b_ssig[c], acc);
            acc = fmaf(W_ps[o*128 + 64 + c], b_tsig[c], acc);
        }
        ws[WS_B0 + o] = acc * sps + be_ps[o];
        const float sraw = g_raw[o] / sqrtf(v_raw[o] + EPSF);
        ws[WS_BC + o] = (b_raw[o] - m_raw[o]) * sraw + be_raw[o];
        const float sfu = g_fu[o] / sqrtf(v_fu[o] + EPSF);
        ws[WS_BF + o] = (b_fu[o] - m_fu[o]) * sfu + be_fu[o];
    } else if (bid < 94) {
        const int i = bid - 85;       // 0..8 = ci*3+kt
        const float sraw = g_raw[o] / sqrtf(v_raw[o] + EPSF);
        ws[WS_WC + i*64 + o] = W_raw[o*9 + i] * sraw;
    } else {
        const int c = bid - 94;       // 0..127
        const float sfu = g_fu[o] / sqrtf(v_fu[o] + EPSF);
        ws[WS_WF + c*64 + o] = W_fu[o*128 + c] * sfu;
    }
}

// one depth-3 signature step with increment d[4]; uses OLD S1,S2 (order matters)
// sig = [S1(0..3) | S2(4..19) | S3(20..83)], all compile-time indexed (registers)
__device__ __forceinline__ void sig_step(float* __restrict__ sig, const float d[4])
{
    float* S1 = sig;
    float* S2 = sig + 4;
    float* S3 = sig + 20;
    float e2[16];
#pragma unroll
    for (int i = 0; i < 4; ++i) {
        const float dh = 0.5f * d[i];
#pragma unroll
        for (int j = 0; j < 4; ++j) e2[i*4+j] = dh * d[j];
    }
    float f[4];
#pragma unroll
    for (int i = 0; i < 4; ++i) f[i] = fmaf(d[i], (1.f/3.f), S1[i]);  // S1 + d/3
#pragma unroll
    for (int i = 0; i < 4; ++i) {
#pragma unroll
        for (int j = 0; j < 4; ++j) {
            const float s2 = S2[i*4+j];
            const float fi = f[i];
#pragma unroll
            for (int k = 0; k < 4; ++k)
                S3[(i*4+j)*4+k] = fmaf(s2, d[k], fmaf(fi, e2[j*4+k], S3[(i*4+j)*4+k]));
        }
    }
#pragma unroll
    for (int i = 0; i < 4; ++i) {
#pragma unroll
        for (int j = 0; j < 4; ++j) S2[i*4+j] = fmaf(S1[i], d[j], S2[i*4+j] + e2[i*4+j]);
    }
#pragma unroll
    for (int i = 0; i < 4; ++i) S1[i] += d[i];
}

// grid: (1, J, B); block 256 (= all of t); thread = one column (b,j,t), lane varies t (coalesced)
// No LDS, no barriers. All sigma values live in registers; GEMVs fully unrolled so
// every weight read is a wave-uniform scalar load and every index is compile-time.
__global__ __launch_bounds__(256, 2) void stem_main(
    const float* __restrict__ x, const int* __restrict__ path,
    const float* __restrict__ ws, float* __restrict__ out)
{
    const int t   = threadIdx.x;      // 0..255
    const int j   = blockIdx.y;
    const int b   = blockIdx.z;
    const float* xb = x + (size_t)b * (3*64*256);

    float sig[84];
#pragma unroll
    for (int i=0;i<84;i++) sig[i]=0.f;

    // ---- spatial signature: points s=0..4, channels (x[b,c,path[j,s],t], s/4) ----
    {
        float pr0=0.f, pr1=0.f, pr2=0.f, pr3=0.f;
#pragma unroll
        for (int s = 0; s < 5; ++s) {
            const int jp = path[j*5 + s];            // wave-uniform
            const float p0 = xb[(0*64 + jp)*256 + t];
            const float p1 = xb[(1*64 + jp)*256 + t];
            const float p2 = xb[(2*64 + jp)*256 + t];
            const float p3 = (float)s * 0.25f;
            const float d[4] = {p0-pr0, p1-pr1, p2-pr2, p3-pr3};
            pr0=p0; pr1=p1; pr2=p2; pr3=p3;
            sig_step(sig, d);
        }
    }

    // acc = bias0 + M_s^T * sigma_s   (fully unrolled: sv from register, w via s_load)
    float acc[64];
#pragma unroll
    for (int o=0;o<64;o++) acc[o] = ws[WS_B0 + o];
#pragma unroll
    for (int k=0;k<84;k++) {
        const float sv = sig[k];
#pragma unroll
        for (int o=0;o<64;o++) acc[o] = fmaf(sv, ws[WS_MS + k*64 + o], acc[o]);
    }

    // ---- temporal signature: the reference's reshape SCRAMBLES (T_LEN,J)->(J,T_LEN):
    // point k reads joint (j*7+k)%64 at time clamp(t + (j*7+k)/64 - 3), time-chan k/6 ----
#pragma unroll
    for (int i=0;i<84;i++) sig[i]=0.f;
    {
        float pr0=0.f, pr1=0.f, pr2=0.f, pr3=0.f;
#pragma unroll
        for (int k=0;k<7;++k) {
            const int idx  = j*7 + k;                // wave-uniform
            const int jsrc = idx & 63;
            const int tl   = idx >> 6;
            const int ts   = min(max(t + tl - 3, 0), 255);
            const float p0 = xb[(0*64 + jsrc)*256 + ts];
            const float p1 = xb[(1*64 + jsrc)*256 + ts];
            const float p2 = xb[(2*64 + jsrc)*256 + ts];
            const float p3 = (float)k * (1.f/6.f);
            const float d[4] = {p0-pr0, p1-pr1, p2-pr2, p3-pr3};
            pr0=p0; pr1=p1; pr2=p2; pr3=p3;
            sig_step(sig, d);
        }
    }
#pragma unroll
    for (int k=0;k<84;k++) {
        const float sv = sig[k];
#pragma unroll
        for (int o=0;o<64;o++) acc[o] = fmaf(sv, ws[WS_MT + k*64 + o], acc[o]);
    }

    // ps BN+ReLU (folded) -> sig column (registers; reuse sig[0..63])
#pragma unroll
    for (int o=0;o<64;o++) sig[o] = fmaxf(acc[o], 0.f);

    // final: acc = bias_f + Wf[64+c]^T sigcol + Wf[c]^T relu(conv_c)
#pragma unroll
    for (int o=0;o<64;o++) acc[o] = ws[WS_BF + o];
#pragma unroll
    for (int c=0;c<64;c++) {
        const float sv = sig[c];
#pragma unroll
        for (int o=0;o<64;o++) acc[o] = fmaf(sv, ws[WS_WF + (64 + c)*64 + o], acc[o]);
    }

    // conv half, fused: compute relu(conv[c]) one at a time (zero-pad in T)
    float xv[9];
#pragma unroll
    for (int ci=0; ci<3; ++ci) {
        const float* xr = xb + (ci*64 + j)*256;
        xv[ci*3+0] = (t >= 1)   ? xr[t-1] : 0.f;
        xv[ci*3+1] = xr[t];
        xv[ci*3+2] = (t <= 254) ? xr[t+1] : 0.f;
    }
#pragma unroll
    for (int c=0;c<64;c++) {
        float cv = ws[WS_BC + c];
#pragma unroll
        for (int i=0;i<9;i++) cv = fmaf(xv[i], ws[WS_WC + i*64 + c], cv);
        cv = fmaxf(cv, 0.f);
#pragma unroll
        for (int o=0;o<64;o++) acc[o] = fmaf(cv, ws[WS_WF + c*64 + o], acc[o]);
    }

    // fu BN+ReLU (folded) and write out[b][o][j][t]
    float* ob = out + ((size_t)b*64*64 + (size_t)j)*256 + t;
#pragma unroll
    for (int o=0;o<64;o++) ob[(size_t)o*(64*256)] = fmaxf(acc[o], 0.f);
}

extern "C" void kernel_launch(void* const* d_in, const int* in_sizes, int n_in,
                              void* d_out, int out_size, void* d_ws, size_t ws_size,
                              hipStream_t stream)
{
    const float* x      = (const float*)d_in[0];
    const int*   path   = (const int*)  d_in[1];
    const float* W_ssig = (const float*)d_in[2];
    const float* b_ssig = (const float*)d_in[3];
    const float* W_tsig = (const float*)d_in[4];
    const float* b_tsig = (const float*)d_in[5];
    const float* W_raw  = (const float*)d_in[6];
    const float* b_raw  = (const float*)d_in[7];
    const float* W_ps   = (const float*)d_in[8];
    const float* b_ps   = (const float*)d_in[9];
    const float* W_fu   = (const float*)d_in[10];
    const float* b_fu   = (const float*)d_in[11];
    const float* g_raw  = (const float*)d_in[12];
    const float* be_raw = (const float*)d_in[13];
    const float* m_raw  = (const float*)d_in[14];
    const float* v_raw  = (const float*)d_in[15];
    const float* g_ps   = (const float*)d_in[16];
    const float* be_ps  = (const float*)d_in[17];
    const float* m_ps   = (const float*)d_in[18];
    const float* v_ps   = (const float*)d_in[19];
    const float* g_fu   = (const float*)d_in[20];
    const float* be_fu  = (const float*)d_in[21];
    const float* m_fu   = (const float*)d_in[22];
    const float* v_fu   = (const float*)d_in[23];
    float* out = (float*)d_out;
    float* ws  = (float*)d_ws;

    stem_prep<<<222, 64, 0, stream>>>(W_ssig, b_ssig, W_tsig, b_tsig, W_raw, b_raw,
                                      W_ps, b_ps, W_fu, b_fu,
                                      g_raw, be_raw, m_raw, v_raw,
                                      g_ps, be_ps, m_ps, v_ps,
                                      g_fu, be_fu, m_fu, v_fu, ws);

    dim3 grid(1, 64, 32);   // (t handled by block, J, B)
    stem_main<<<grid, 256, 0, stream>>>(x, path, ws, out);
}

// Round 3
// 680.717 us; speedup vs baseline: 3.8824x; 3.8824x over previous
//
#include <hip/hip_runtime.h>
#include <cstdint>

#define EPSF 1e-5f

// workspace layout (float offsets)
#define WS_MS 0        // M_s  [k=84][o=64]
#define WS_MT 5376     // M_t  [k=84][o=64]
#define WS_B0 10752    // bias0 [64]  (folded ps-BN bias)
#define WS_WC 10816    // conv w folded [c=64][i=9]
#define WS_BC 11392    // conv bias folded [64]
#define WS_WF 11456    // W_fu folded [c=128][o=64]
#define WS_BF 19648    // fu bias folded [64]
#define WS_TOTAL 19712

__global__ __launch_bounds__(64) void stem_prep(
    const float* __restrict__ W_ssig, const float* __restrict__ b_ssig,
    const float* __restrict__ W_tsig, const float* __restrict__ b_tsig,
    const float* __restrict__ W_raw,  const float* __restrict__ b_raw,
    const float* __restrict__ W_ps,   const float* __restrict__ b_ps,
    const float* __restrict__ W_fu,   const float* __restrict__ b_fu,
    const float* __restrict__ g_raw, const float* __restrict__ be_raw,
    const float* __restrict__ m_raw, const float* __restrict__ v_raw,
    const float* __restrict__ g_ps,  const float* __restrict__ be_ps,
    const float* __restrict__ m_ps,  const float* __restrict__ v_ps,
    const float* __restrict__ g_fu,  const float* __restrict__ be_fu,
    const float* __restrict__ m_fu,  const float* __restrict__ v_fu,
    float* __restrict__ ws)
{
    const int o = threadIdx.x;        // 0..63 output channel
    const int bid = blockIdx.x;
    if (bid < 84) {
        const int k = bid;
        const float sps = g_ps[o] / sqrtf(v_ps[o] + EPSF);
        float accs = 0.f, acct = 0.f;
        for (int c = 0; c < 64; ++c) {
            accs = fmaf(W_ps[o*128 + c],      W_ssig[c*84 + k], accs);
            acct = fmaf(W_ps[o*128 + 64 + c], W_tsig[c*84 + k], acct);
        }
        ws[WS_MS + k*64 + o] = accs * sps;
        ws[WS_MT + k*64 + o] = acct * sps;
    } else if (bid == 84) {
        const float sps = g_ps[o] / sqrtf(v_ps[o] + EPSF);
        float acc = b_ps[o] - m_ps[o];
        for (int c = 0; c < 64; ++c) {
            acc = fmaf(W_ps[o*128 + c],      b_ssig[c], acc);
            acc = fmaf(W_ps[o*128 + 64 + c], b_tsig[c], acc);
        }
        ws[WS_B0 + o] = acc * sps + be_ps[o];
        const float sraw = g_raw[o] / sqrtf(v_raw[o] + EPSF);
        ws[WS_BC + o] = (b_raw[o] - m_raw[o]) * sraw + be_raw[o];
        const float sfu = g_fu[o] / sqrtf(v_fu[o] + EPSF);
        ws[WS_BF + o] = (b_fu[o] - m_fu[o]) * sfu + be_fu[o];
    } else if (bid < 94) {
        const int i = bid - 85;       // 0..8 = ci*3+kt ; layout [c][i] for contiguous per-c reads
        const float sraw = g_raw[o] / sqrtf(v_raw[o] + EPSF);
        ws[WS_WC + o*9 + i] = W_raw[o*9 + i] * sraw;
    } else {
        const int c = bid - 94;       // 0..127
        const float sfu = g_fu[o] / sqrtf(v_fu[o] + EPSF);
        ws[WS_WF + c*64 + o] = W_fu[o*128 + c] * sfu;
    }
}

// one depth-3 signature step with increment d[4]; uses OLD S1,S2 (order matters)
// sig = [S1(0..3) | S2(4..19) | S3(20..83)], all compile-time indexed (registers)
__device__ __forceinline__ void sig_step(float* __restrict__ sig, const float d[4])
{
    float* S1 = sig;
    float* S2 = sig + 4;
    float* S3 = sig + 20;
    float e2[16];
#pragma unroll
    for (int i = 0; i < 4; ++i) {
        const float dh = 0.5f * d[i];
#pragma unroll
        for (int j = 0; j < 4; ++j) e2[i*4+j] = dh * d[j];
    }
    float f[4];
#pragma unroll
    for (int i = 0; i < 4; ++i) f[i] = fmaf(d[i], (1.f/3.f), S1[i]);  // S1 + d/3
#pragma unroll
    for (int i = 0; i < 4; ++i) {
#pragma unroll
        for (int j = 0; j < 4; ++j) {
            const float s2 = S2[i*4+j];
            const float fi = f[i];
#pragma unroll
            for (int k = 0; k < 4; ++k)
                S3[(i*4+j)*4+k] = fmaf(s2, d[k], fmaf(fi, e2[j*4+k], S3[(i*4+j)*4+k]));
        }
    }
#pragma unroll
    for (int i = 0; i < 4; ++i) {
#pragma unroll
        for (int j = 0; j < 4; ++j) S2[i*4+j] = fmaf(S1[i], d[j], S2[i*4+j] + e2[i*4+j]);
    }
#pragma unroll
    for (int i = 0; i < 4; ++i) S1[i] += d[i];
}

// grid: (2, J, B); block 128; thread = one column (b,j,t), lane varies t (coalesced).
// sigma in registers (compile-time indexed); GEMVs chunked 8-wide so live set ~105 VGPR;
// ps intermediate in LDS [64][128] (lane-indexed, 2-way = conflict-free). No barriers
// (each thread touches only its own tid slice).
__global__ __launch_bounds__(128, 3) void stem_main(
    const float* __restrict__ x, const int* __restrict__ path,
    const float* __restrict__ ws, float* __restrict__ out)
{
    __shared__ float ps_lds[64 * 128];   // [o][tid]
    const int tid = threadIdx.x;
    const int t   = blockIdx.x * 128 + tid;
    const int j   = blockIdx.y;
    const int b   = blockIdx.z;
    const float* xb = x + (size_t)b * (3*64*256);

    float sig[84];
#pragma unroll
    for (int i=0;i<84;i++) sig[i]=0.f;

    // ---- spatial signature: points s=0..4, channels (x[b,c,path[j,s],t], s/4) ----
    {
        float pr0=0.f, pr1=0.f, pr2=0.f, pr3=0.f;
        int jp = path[j*5 + 0];
        float n0 = xb[(0*64 + jp)*256 + t];
        float n1 = xb[(1*64 + jp)*256 + t];
        float n2 = xb[(2*64 + jp)*256 + t];
#pragma unroll 1
        for (int s = 0; s < 5; ++s) {
            const float p0 = n0, p1 = n1, p2 = n2;
            const float p3 = (float)s * 0.25f;
            const int sn = (s < 4) ? s + 1 : 4;          // prefetch next point
            jp = path[j*5 + sn];
            n0 = xb[(0*64 + jp)*256 + t];
            n1 = xb[(1*64 + jp)*256 + t];
            n2 = xb[(2*64 + jp)*256 + t];
            const float d[4] = {p0-pr0, p1-pr1, p2-pr2, p3-pr3};
            pr0=p0; pr1=p1; pr2=p2; pr3=p3;
            sig_step(sig, d);
        }
    }

    // ---- GEMV-s in 8-wide output chunks: ps_chunk = B0 + M_s^T sigma_s -> LDS ----
#pragma unroll 1
    for (int oc = 0; oc < 64; oc += 8) {
        float a[8];
#pragma unroll
        for (int i=0;i<8;i++) a[i] = ws[WS_B0 + oc + i];
#pragma unroll
        for (int k=0;k<84;k++) {
            const float sv = sig[k];
            const float* w = ws + WS_MS + k*64 + oc;     // uniform -> s_load
#pragma unroll
            for (int i=0;i<8;i++) a[i] = fmaf(sv, w[i], a[i]);
        }
#pragma unroll
        for (int i=0;i<8;i++) ps_lds[(oc+i)*128 + tid] = a[i];
    }

    // ---- temporal signature: the reference's reshape SCRAMBLES (T_LEN,J)->(J,T_LEN):
    // point k reads joint (j*7+k)%64 at time clamp(t + (j*7+k)/64 - 3), time-chan k/6 ----
#pragma unroll
    for (int i=0;i<84;i++) sig[i]=0.f;
    {
        float pr0=0.f, pr1=0.f, pr2=0.f, pr3=0.f;
        int idx = j*7;
        int jsrc = idx & 63, tl = idx >> 6;
        int ts0 = min(max(t + tl - 3, 0), 255);
        float n0 = xb[(0*64 + jsrc)*256 + ts0];
        float n1 = xb[(1*64 + jsrc)*256 + ts0];
        float n2 = xb[(2*64 + jsrc)*256 + ts0];
#pragma unroll 1
        for (int k=0;k<7;++k) {
            const float p0=n0, p1=n1, p2=n2;
            const float p3 = (float)k * (1.f/6.f);
            const int kn = (k<6)? k+1 : 6;
            idx = j*7 + kn; jsrc = idx & 63; tl = idx >> 6;
            const int tsn = min(max(t + tl - 3, 0), 255);
            n0 = xb[(0*64 + jsrc)*256 + tsn];
            n1 = xb[(1*64 + jsrc)*256 + tsn];
            n2 = xb[(2*64 + jsrc)*256 + tsn];
            const float d[4] = {p0-pr0, p1-pr1, p2-pr2, p3-pr3};
            pr0=p0; pr1=p1; pr2=p2; pr3=p3;
            sig_step(sig, d);
        }
    }

    // ---- GEMV-t chunks: ps = relu(ps_partial + M_t^T sigma_t) (in LDS) ----
#pragma unroll 1
    for (int oc = 0; oc < 64; oc += 8) {
        float a[8];
#pragma unroll
        for (int i=0;i<8;i++) a[i] = ps_lds[(oc+i)*128 + tid];
#pragma unroll
        for (int k=0;k<84;k++) {
            const float sv = sig[k];
            const float* w = ws + WS_MT + k*64 + oc;
#pragma unroll
            for (int i=0;i<8;i++) a[i] = fmaf(sv, w[i], a[i]);
        }
#pragma unroll
        for (int i=0;i<8;i++) ps_lds[(oc+i)*128 + tid] = fmaxf(a[i], 0.f);
    }

    // ---- final: accF = bias_f + Wf_hi^T ps + Wf_lo^T relu(conv) ----
    float accF[64];
#pragma unroll
    for (int o=0;o<64;o++) accF[o] = ws[WS_BF + o];

    float xv[9];
#pragma unroll
    for (int ci=0; ci<3; ++ci) {
        const float* xr = xb + (ci*64 + j)*256;
        xv[ci*3+0] = (t >= 1)   ? xr[t-1] : 0.f;   // conv zero-pads in T
        xv[ci*3+1] = xr[t];
        xv[ci*3+2] = (t <= 254) ? xr[t+1] : 0.f;
    }
#pragma unroll 2
    for (int c=0;c<64;c++) {
        const float pv = ps_lds[c*128 + tid];
        float cv = ws[WS_BC + c];
        const float* wc = ws + WS_WC + c*9;          // contiguous 9 floats, uniform
#pragma unroll
        for (int i=0;i<9;i++) cv = fmaf(xv[i], wc[i], cv);
        cv = fmaxf(cv, 0.f);
        const float* wlo = ws + WS_WF + c*64;        // conv half of W_fu
        const float* whi = ws + WS_WF + (64 + c)*64; // sig half of W_fu
#pragma unroll
        for (int o=0;o<64;o++) accF[o] = fmaf(pv, whi[o], fmaf(cv, wlo[o], accF[o]));
    }

    // fu BN+ReLU (folded) and write out[b][o][j][t]
    float* ob = out + ((size_t)b*64*64 + (size_t)j)*256 + t;
#pragma unroll
    for (int o=0;o<64;o++) ob[(size_t)o*(64*256)] = fmaxf(accF[o], 0.f);
}

extern "C" void kernel_launch(void* const* d_in, const int* in_sizes, int n_in,
                              void* d_out, int out_size, void* d_ws, size_t ws_size,
                              hipStream_t stream)
{
    const float* x      = (const float*)d_in[0];
    const int*   path   = (const int*)  d_in[1];
    const float* W_ssig = (const float*)d_in[2];
    const float* b_ssig = (const float*)d_in[3];
    const float* W_tsig = (const float*)d_in[4];
    const float* b_tsig = (const float*)d_in[5];
    const float* W_raw  = (const float*)d_in[6];
    const float* b_raw  = (const float*)d_in[7];
    const float* W_ps   = (const float*)d_in[8];
    const float* b_ps   = (const float*)d_in[9];
    const float* W_fu   = (const float*)d_in[10];
    const float* b_fu   = (const float*)d_in[11];
    const float* g_raw  = (const float*)d_in[12];
    const float* be_raw = (const float*)d_in[13];
    const float* m_raw  = (const float*)d_in[14];
    const float* v_raw  = (const float*)d_in[15];
    const float* g_ps   = (const float*)d_in[16];
    const float* be_ps  = (const float*)d_in[17];
    const float* m_ps   = (const float*)d_in[18];
    const float* v_ps   = (const float*)d_in[19];
    const float* g_fu   = (const float*)d_in[20];
    const float* be_fu  = (const float*)d_in[21];
    const float* m_fu   = (const float*)d_in[22];
    const float* v_fu   = (const float*)d_in[23];
    float* out = (float*)d_out;
    float* ws  = (float*)d_ws;

    stem_prep<<<222, 64, 0, stream>>>(W_ssig, b_ssig, W_tsig, b_tsig, W_raw, b_raw,
                                      W_ps, b_ps, W_fu, b_fu,
                                      g_raw, be_raw, m_raw, v_raw,
                                      g_ps, be_ps, m_ps, v_ps,
                                      g_fu, be_fu, m_fu, v_fu, ws);

    dim3 grid(2, 64, 32);   // (t-chunks, J, B)
    stem_main<<<grid, 128, 0, stream>>>(x, path, ws, out);
}

// Round 5
// 105.041 us; speedup vs baseline: 25.1600x; 6.4805x over previous
//
#include <hip/hip_runtime.h>
#include <cstdint>

#define EPSF 1e-5f

typedef __attribute__((ext_vector_type(8))) short     bf16x8;
typedef __attribute__((ext_vector_type(4))) float     f32x4;
typedef __attribute__((ext_vector_type(4))) unsigned int uint32x4;
typedef __attribute__((ext_vector_type(2))) unsigned int uint32x2;

// ---- workspace layout ----
// floats (at byte 0): B0[64] @0, BC[64] @64, BF[64] @128, WC[64*9] @192  (ends 768 floats)
#define WS_B0 0
#define WS_BC 64
#define WS_BF 128
#define WS_WC 192
// bf16 A-fragments: wsA1 at byte 4096 (24 frags * 64 lanes * 8 = 12288 ushort)
//                   wsA2 at byte 28672 (16 frags * 64 lanes * 8 =  8192 ushort)

__device__ __forceinline__ unsigned short f2bf(float f) {
    union { float f; unsigned u; } v; v.f = f;
    unsigned r = v.u + 0x7fffu + ((v.u >> 16) & 1u);   // RNE
    return (unsigned short)(r >> 16);
}

// ---------------- prep: fold BNs, collapse W_ps@{W_ssig,W_tsig}, pack MFMA A-frags ----------------
__global__ __launch_bounds__(64) void stem_prep(
    const float* __restrict__ W_ssig, const float* __restrict__ b_ssig,
    const float* __restrict__ W_tsig, const float* __restrict__ b_tsig,
    const float* __restrict__ W_raw,  const float* __restrict__ b_raw,
    const float* __restrict__ W_ps,   const float* __restrict__ b_ps,
    const float* __restrict__ W_fu,   const float* __restrict__ b_fu,
    const float* __restrict__ g_raw, const float* __restrict__ be_raw,
    const float* __restrict__ m_raw, const float* __restrict__ v_raw,
    const float* __restrict__ g_ps,  const float* __restrict__ be_ps,
    const float* __restrict__ m_ps,  const float* __restrict__ v_ps,
    const float* __restrict__ g_fu,  const float* __restrict__ be_fu,
    const float* __restrict__ m_fu,  const float* __restrict__ v_fu,
    float* __restrict__ wsf, unsigned short* __restrict__ wsA1,
    unsigned short* __restrict__ wsA2)
{
    const int l = threadIdx.x;         // 0..63
    const int f = blockIdx.x;
    if (f < 24) {
        // A1 frag f = h*12 + s*4 + to ; element b: W1[k=s*32+8*(l>>4)+b][o=to*16+(l&15)]
        const int h = f / 12, rem = f % 12, s = rem / 4, to = rem % 4;
        const int o = to*16 + (l & 15);
        const float sps = g_ps[o] / sqrtf(v_ps[o] + EPSF);
        const float* wp  = W_ps + o*128 + 64*h;
        const float* wsg = h ? W_tsig : W_ssig;
        for (int b = 0; b < 8; ++b) {
            const int k = s*32 + ((l >> 4) * 8) + b;
            float v = 0.f;
            if (k < 84) {
                float acc = 0.f;
                for (int c = 0; c < 64; ++c) acc = fmaf(wp[c], wsg[c*84 + k], acc);
                v = acc * sps;
            }
            wsA1[f*512 + l*8 + b] = f2bf(v);
        }
    } else if (f < 40) {
        // A2 frag q = s*4+to ; element b: Wf[c=s*32+8*(l>>4)+b][o] = sfu[o]*W_fu[o*128+c]
        const int q = f - 24, s = q / 4, to = q % 4;
        const int o = to*16 + (l & 15);
        const float sfu = g_fu[o] / sqrtf(v_fu[o] + EPSF);
        for (int b = 0; b < 8; ++b) {
            const int c = s*32 + ((l >> 4) * 8) + b;
            wsA2[q*512 + l*8 + b] = f2bf(W_fu[o*128 + c] * sfu);
        }
    } else {
        const int o = l;
        const float sps = g_ps[o] / sqrtf(v_ps[o] + EPSF);
        float acc = b_ps[o] - m_ps[o];
        for (int c = 0; c < 64; ++c) {
            acc = fmaf(W_ps[o*128 + c],      b_ssig[c], acc);
            acc = fmaf(W_ps[o*128 + 64 + c], b_tsig[c], acc);
        }
        wsf[WS_B0 + o] = acc * sps + be_ps[o];
        const float sraw = g_raw[o] / sqrtf(v_raw[o] + EPSF);
        wsf[WS_BC + o] = (b_raw[o] - m_raw[o]) * sraw + be_raw[o];
        const float sfu = g_fu[o] / sqrtf(v_fu[o] + EPSF);
        wsf[WS_BF + o] = (b_fu[o] - m_fu[o]) * sfu + be_fu[o];
        for (int i = 0; i < 9; ++i) wsf[WS_WC + o*9 + i] = W_raw[o*9 + i] * sraw;
    }
}

// one depth-3 signature step; sig = [S1(0..3)|S2(4..19)|S3(20..83)], all static-indexed
__device__ __forceinline__ void sig_step(float* __restrict__ sig, const float d[4])
{
    float* S1 = sig; float* S2 = sig + 4; float* S3 = sig + 20;
    float e2[16];
#pragma unroll
    for (int i = 0; i < 4; ++i) {
        const float dh = 0.5f * d[i];
#pragma unroll
        for (int j = 0; j < 4; ++j) e2[i*4+j] = dh * d[j];
    }
    float fv[4];
#pragma unroll
    for (int i = 0; i < 4; ++i) fv[i] = fmaf(d[i], (1.f/3.f), S1[i]);
#pragma unroll
    for (int i = 0; i < 4; ++i) {
#pragma unroll
        for (int j = 0; j < 4; ++j) {
            const float s2 = S2[i*4+j]; const float fi = fv[i];
#pragma unroll
            for (int k = 0; k < 4; ++k)
                S3[(i*4+j)*4+k] = fmaf(s2, d[k], fmaf(fi, e2[j*4+k], S3[(i*4+j)*4+k]));
        }
    }
#pragma unroll
    for (int i = 0; i < 4; ++i)
#pragma unroll
        for (int j = 0; j < 4; ++j) S2[i*4+j] = fmaf(S1[i], d[j], S2[i*4+j] + e2[i*4+j]);
#pragma unroll
    for (int i = 0; i < 4; ++i) S1[i] += d[i];
}

// pack sig[84] (+12 zero pad) into LDS row as bf16
__device__ __forceinline__ void sig_to_lds(const float* __restrict__ sig,
                                           unsigned short* __restrict__ row)
{
    unsigned uu[48];
#pragma unroll
    for (int i = 0; i < 42; ++i)
        uu[i] = (unsigned)f2bf(sig[2*i]) | ((unsigned)f2bf(sig[2*i+1]) << 16);
#pragma unroll
    for (int i = 42; i < 48; ++i) uu[i] = 0u;
    uint32x4* rp = (uint32x4*)row;
#pragma unroll
    for (int i = 0; i < 12; ++i) {
        uint32x4 v = { uu[4*i], uu[4*i+1], uu[4*i+2], uu[4*i+3] };
        rp[i] = v;
    }
}

// grid: (4 t-chunks, 64 j, 32 b); block 64 = 1 wave; block owns t-cols [bx*64, bx*64+64).
// LDS hand-offs are cross-lane -> explicit __syncthreads() at every write->read and
// read->write boundary (round-4 failure: compiler hoisted provably-non-self-aliasing
// B-tile ds_reads above the sig ds_writes).
__global__ __launch_bounds__(64, 2) void stem_main(
    const float* __restrict__ x, const int* __restrict__ path,
    const float* __restrict__ wsf, const unsigned short* __restrict__ wsA1,
    const unsigned short* __restrict__ wsA2, float* __restrict__ out)
{
    __shared__ unsigned short sbuf[64 * 136];   // 17408 B; sig rows stride 104, u rows stride 136
    const int l  = threadIdx.x;                  // lane
    const int t  = blockIdx.x * 64 + l;          // global t for this thread's column
    const int j  = blockIdx.y;
    const int b  = blockIdx.z;
    const float* xb = x + (size_t)b * (3*64*256);

    const int lg = l >> 4;      // lane k-group
    const int li = l & 15;      // m/n index within tile

    // conv window loads issued early (held in regs; zero-pad in T)
    float xv[9];
#pragma unroll
    for (int ci = 0; ci < 3; ++ci) {
        const float* xr = xb + (ci*64 + j)*256;
        xv[ci*3+0] = (t >= 1)   ? xr[t-1] : 0.f;
        xv[ci*3+1] = xr[t];
        xv[ci*3+2] = (t <= 254) ? xr[t+1] : 0.f;
    }

    // ---- sigma_s (registers) -> LDS bf16 ----
    float sig[84];
#pragma unroll
    for (int i = 0; i < 84; ++i) sig[i] = 0.f;
    {
        float pr0=0.f, pr1=0.f, pr2=0.f, pr3=0.f;
#pragma unroll
        for (int s = 0; s < 5; ++s) {
            const int jp = path[j*5 + s];                 // wave-uniform
            const float p0 = xb[(0*64 + jp)*256 + t];
            const float p1 = xb[(1*64 + jp)*256 + t];
            const float p2 = xb[(2*64 + jp)*256 + t];
            const float p3 = (float)s * 0.25f;
            const float d[4] = { p0-pr0, p1-pr1, p2-pr2, p3-pr3 };
            pr0=p0; pr1=p1; pr2=p2; pr3=p3;
            sig_step(sig, d);
        }
    }
    sig_to_lds(sig, &sbuf[l*104]);
    __syncthreads();                                      // W->R: sig rows ready

    // ---- GEMM1a: acc += A(h=0) * sigma_s ----
    f32x4 acc[4][4];
#pragma unroll
    for (int a = 0; a < 4; ++a)
#pragma unroll
        for (int c = 0; c < 4; ++c) acc[a][c] = (f32x4){0.f,0.f,0.f,0.f};

    {
#pragma unroll
        for (int s = 0; s < 3; ++s) {
#pragma unroll
            for (int tt = 0; tt < 4; ++tt) {
                const bf16x8 B = *(const bf16x8*)(&sbuf[(tt*16 + li)*104 + s*32 + lg*8]);
#pragma unroll
                for (int to = 0; to < 4; ++to) {
                    const bf16x8 A = *(const bf16x8*)(wsA1 + ((0*3+s)*4+to)*512 + l*8);
                    acc[to][tt] = __builtin_amdgcn_mfma_f32_16x16x32_bf16(A, B, acc[to][tt], 0, 0, 0);
                }
            }
        }
    }
    __syncthreads();                                      // R->W: done reading sigma_s rows

    // ---- sigma_t (registers) -> same LDS rows ----
#pragma unroll
    for (int i = 0; i < 84; ++i) sig[i] = 0.f;
    {
        float pr0=0.f, pr1=0.f, pr2=0.f, pr3=0.f;
#pragma unroll
        for (int k = 0; k < 7; ++k) {
            const int idx  = j*7 + k;                     // scrambled temporal window
            const int jsrc = idx & 63;
            const int tl   = idx >> 6;
            const int ts   = min(max(t + tl - 3, 0), 255);
            const float p0 = xb[(0*64 + jsrc)*256 + ts];
            const float p1 = xb[(1*64 + jsrc)*256 + ts];
            const float p2 = xb[(2*64 + jsrc)*256 + ts];
            const float p3 = (float)k * (1.f/6.f);
            const float d[4] = { p0-pr0, p1-pr1, p2-pr2, p3-pr3 };
            pr0=p0; pr1=p1; pr2=p2; pr3=p3;
            sig_step(sig, d);
        }
    }
    sig_to_lds(sig, &sbuf[l*104]);
    __syncthreads();                                      // W->R: sigma_t rows ready

    // ---- GEMM1b: acc += A(h=1) * sigma_t ----
    {
#pragma unroll
        for (int s = 0; s < 3; ++s) {
#pragma unroll
            for (int tt = 0; tt < 4; ++tt) {
                const bf16x8 B = *(const bf16x8*)(&sbuf[(tt*16 + li)*104 + s*32 + lg*8]);
#pragma unroll
                for (int to = 0; to < 4; ++to) {
                    const bf16x8 A = *(const bf16x8*)(wsA1 + ((1*3+s)*4+to)*512 + l*8);
                    acc[to][tt] = __builtin_amdgcn_mfma_f32_16x16x32_bf16(A, B, acc[to][tt], 0, 0, 0);
                }
            }
        }
    }
    __syncthreads();                                      // R->W: done reading sigma_t rows

    // ---- ps epilogue: u[t][64+o] = bf16(relu(acc + B0))  (C/D: col=li -> t, row=lg*4+r -> o) ----
#pragma unroll
    for (int to = 0; to < 4; ++to) {
        const f32x4 b0 = *(const f32x4*)(wsf + WS_B0 + to*16 + lg*4);
#pragma unroll
        for (int tt = 0; tt < 4; ++tt) {
            const unsigned lo = (unsigned)f2bf(fmaxf(acc[to][tt][0] + b0[0], 0.f))
                              | ((unsigned)f2bf(fmaxf(acc[to][tt][1] + b0[1], 0.f)) << 16);
            const unsigned hi = (unsigned)f2bf(fmaxf(acc[to][tt][2] + b0[2], 0.f))
                              | ((unsigned)f2bf(fmaxf(acc[to][tt][3] + b0[3], 0.f)) << 16);
            uint32x2 w = { lo, hi };
            *(uint32x2*)(&sbuf[(tt*16 + li)*136 + 64 + to*16 + lg*4]) = w;
        }
    }

    // ---- conv half: u[t][c<64] = bf16(relu(conv_c)) ----
    {
        unsigned cu[32];
#pragma unroll
        for (int cc = 0; cc < 32; ++cc) {
            float v0 = wsf[WS_BC + 2*cc];
            float v1 = wsf[WS_BC + 2*cc + 1];
#pragma unroll
            for (int i = 0; i < 9; ++i) {
                v0 = fmaf(xv[i], wsf[WS_WC + (2*cc)*9 + i], v0);
                v1 = fmaf(xv[i], wsf[WS_WC + (2*cc+1)*9 + i], v1);
            }
            cu[cc] = (unsigned)f2bf(fmaxf(v0, 0.f)) | ((unsigned)f2bf(fmaxf(v1, 0.f)) << 16);
        }
        uint32x4* up = (uint32x4*)(&sbuf[l*136]);
#pragma unroll
        for (int i = 0; i < 8; ++i) {
            uint32x4 v = { cu[4*i], cu[4*i+1], cu[4*i+2], cu[4*i+3] };
            up[i] = v;
        }
    }
    __syncthreads();                                      // W->R: u rows ready

    // ---- GEMM2: out = relu(Wf^T u + BF) ----
#pragma unroll
    for (int a = 0; a < 4; ++a)
#pragma unroll
        for (int c = 0; c < 4; ++c) acc[a][c] = (f32x4){0.f,0.f,0.f,0.f};
    {
#pragma unroll
        for (int s = 0; s < 4; ++s) {
#pragma unroll
            for (int tt = 0; tt < 4; ++tt) {
                const bf16x8 B = *(const bf16x8*)(&sbuf[(tt*16 + li)*136 + s*32 + lg*8]);
#pragma unroll
                for (int to = 0; to < 4; ++to) {
                    const bf16x8 A = *(const bf16x8*)(wsA2 + (s*4+to)*512 + l*8);
                    acc[to][tt] = __builtin_amdgcn_mfma_f32_16x16x32_bf16(A, B, acc[to][tt], 0, 0, 0);
                }
            }
        }
    }

    // ---- final epilogue: add BF, relu, store out[b][o][j][t] ----
#pragma unroll
    for (int to = 0; to < 4; ++to) {
        const f32x4 bf4 = *(const f32x4*)(wsf + WS_BF + to*16 + lg*4);
#pragma unroll
        for (int tt = 0; tt < 4; ++tt) {
            const int tg = blockIdx.x*64 + tt*16 + li;
#pragma unroll
            for (int r = 0; r < 4; ++r) {
                const int o = to*16 + lg*4 + r;
                out[(((size_t)b*64 + o)*64 + j)*256 + tg] = fmaxf(acc[to][tt][r] + bf4[r], 0.f);
            }
        }
    }
}

extern "C" void kernel_launch(void* const* d_in, const int* in_sizes, int n_in,
                              void* d_out, int out_size, void* d_ws, size_t ws_size,
                              hipStream_t stream)
{
    const float* x      = (const float*)d_in[0];
    const int*   path   = (const int*)  d_in[1];
    const float* W_ssig = (const float*)d_in[2];
    const float* b_ssig = (const float*)d_in[3];
    const float* W_tsig = (const float*)d_in[4];
    const float* b_tsig = (const float*)d_in[5];
    const float* W_raw  = (const float*)d_in[6];
    const float* b_raw  = (const float*)d_in[7];
    const float* W_ps   = (const float*)d_in[8];
    const float* b_ps   = (const float*)d_in[9];
    const float* W_fu   = (const float*)d_in[10];
    const float* b_fu   = (const float*)d_in[11];
    const float* g_raw  = (const float*)d_in[12];
    const float* be_raw = (const float*)d_in[13];
    const float* m_raw  = (const float*)d_in[14];
    const float* v_raw  = (const float*)d_in[15];
    const float* g_ps   = (const float*)d_in[16];
    const float* be_ps  = (const float*)d_in[17];
    const float* m_ps   = (const float*)d_in[18];
    const float* v_ps   = (const float*)d_in[19];
    const float* g_fu   = (const float*)d_in[20];
    const float* be_fu  = (const float*)d_in[21];
    const float* m_fu   = (const float*)d_in[22];
    const float* v_fu   = (const float*)d_in[23];
    float* out = (float*)d_out;

    float*          wsf  = (float*)d_ws;
    unsigned short* wsA1 = (unsigned short*)((char*)d_ws + 4096);
    unsigned short* wsA2 = (unsigned short*)((char*)d_ws + 28672);

    stem_prep<<<41, 64, 0, stream>>>(W_ssig, b_ssig, W_tsig, b_tsig, W_raw, b_raw,
                                     W_ps, b_ps, W_fu, b_fu,
                                     g_raw, be_raw, m_raw, v_raw,
                                     g_ps, be_ps, m_ps, v_ps,
                                     g_fu, be_fu, m_fu, v_fu, wsf, wsA1, wsA2);

    dim3 grid(4, 64, 32);   // (t-chunks, J, B)
    stem_main<<<grid, 64, 0, stream>>>(x, path, wsf, wsA1, wsA2, out);
}

// Round 6
// 90.681 us; speedup vs baseline: 29.1442x; 1.1584x over previous
//
#include <hip/hip_runtime.h>
#include <cstdint>

#define EPSF 1e-5f

typedef __attribute__((ext_vector_type(8))) short     bf16x8;
typedef __attribute__((ext_vector_type(4))) float     f32x4;
typedef __attribute__((ext_vector_type(4))) unsigned int uint32x4;
typedef __attribute__((ext_vector_type(2))) unsigned int uint32x2;

// ---- workspace layout ----
// floats (at byte 0): B0[64] @0, BC[64] @64, BF[64] @128, WC[64*9] @192  (ends 768 floats)
#define WS_B0 0
#define WS_BC 64
#define WS_BF 128
#define WS_WC 192
// bf16 A-fragments: wsA1 at byte 4096 (24 frags * 64 lanes * 8 = 12288 ushort)
//                   wsA2 at byte 28672 (16 frags * 64 lanes * 8 =  8192 ushort)

__device__ __forceinline__ unsigned short f2bf(float f) {
    union { float f; unsigned u; } v; v.f = f;
    unsigned r = v.u + 0x7fffu + ((v.u >> 16) & 1u);   // RNE
    return (unsigned short)(r >> 16);
}

// packed f32x2 -> bf16x2 (RNE), single HW instruction on gfx950
__device__ __forceinline__ unsigned cvtpk(float lo, float hi) {
    unsigned r;
    asm("v_cvt_pk_bf16_f32 %0, %1, %2" : "=v"(r) : "v"(lo), "v"(hi));
    return r;
}

// ---------------- prep: fold BNs, collapse W_ps@{W_ssig,W_tsig}, pack MFMA A-frags ----------------
__global__ __launch_bounds__(64) void stem_prep(
    const float* __restrict__ W_ssig, const float* __restrict__ b_ssig,
    const float* __restrict__ W_tsig, const float* __restrict__ b_tsig,
    const float* __restrict__ W_raw,  const float* __restrict__ b_raw,
    const float* __restrict__ W_ps,   const float* __restrict__ b_ps,
    const float* __restrict__ W_fu,   const float* __restrict__ b_fu,
    const float* __restrict__ g_raw, const float* __restrict__ be_raw,
    const float* __restrict__ m_raw, const float* __restrict__ v_raw,
    const float* __restrict__ g_ps,  const float* __restrict__ be_ps,
    const float* __restrict__ m_ps,  const float* __restrict__ v_ps,
    const float* __restrict__ g_fu,  const float* __restrict__ be_fu,
    const float* __restrict__ m_fu,  const float* __restrict__ v_fu,
    float* __restrict__ wsf, unsigned short* __restrict__ wsA1,
    unsigned short* __restrict__ wsA2)
{
    const int l = threadIdx.x;         // 0..63
    const int f = blockIdx.x;
    if (f < 24) {
        // A1 frag f = h*12 + s*4 + to ; element b: W1[k=s*32+8*(l>>4)+b][o=to*16+(l&15)]
        const int h = f / 12, rem = f % 12, s = rem / 4, to = rem % 4;
        const int o = to*16 + (l & 15);
        const float sps = g_ps[o] / sqrtf(v_ps[o] + EPSF);
        const float* wp  = W_ps + o*128 + 64*h;
        const float* wsg = h ? W_tsig : W_ssig;
        for (int b = 0; b < 8; ++b) {
            const int k = s*32 + ((l >> 4) * 8) + b;
            float v = 0.f;
            if (k < 84) {
                float acc = 0.f;
                for (int c = 0; c < 64; ++c) acc = fmaf(wp[c], wsg[c*84 + k], acc);
                v = acc * sps;
            }
            wsA1[f*512 + l*8 + b] = f2bf(v);
        }
    } else if (f < 40) {
        // A2 frag q = s*4+to ; element b: Wf[c=s*32+8*(l>>4)+b][o] = sfu[o]*W_fu[o*128+c]
        const int q = f - 24, s = q / 4, to = q % 4;
        const int o = to*16 + (l & 15);
        const float sfu = g_fu[o] / sqrtf(v_fu[o] + EPSF);
        for (int b = 0; b < 8; ++b) {
            const int c = s*32 + ((l >> 4) * 8) + b;
            wsA2[q*512 + l*8 + b] = f2bf(W_fu[o*128 + c] * sfu);
        }
    } else {
        const int o = l;
        const float sps = g_ps[o] / sqrtf(v_ps[o] + EPSF);
        float acc = b_ps[o] - m_ps[o];
        for (int c = 0; c < 64; ++c) {
            acc = fmaf(W_ps[o*128 + c],      b_ssig[c], acc);
            acc = fmaf(W_ps[o*128 + 64 + c], b_tsig[c], acc);
        }
        wsf[WS_B0 + o] = acc * sps + be_ps[o];
        const float sraw = g_raw[o] / sqrtf(v_raw[o] + EPSF);
        wsf[WS_BC + o] = (b_raw[o] - m_raw[o]) * sraw + be_raw[o];
        const float sfu = g_fu[o] / sqrtf(v_fu[o] + EPSF);
        wsf[WS_BF + o] = (b_fu[o] - m_fu[o]) * sfu + be_fu[o];
        for (int i = 0; i < 9; ++i) wsf[WS_WC + o*9 + i] = W_raw[o*9 + i] * sraw;
    }
}

// one depth-3 signature step; sig = [S1(0..3)|S2(4..19)|S3(20..83)], all static-indexed
__device__ __forceinline__ void sig_step(float* __restrict__ sig, const float d[4])
{
    float* S1 = sig; float* S2 = sig + 4; float* S3 = sig + 20;
    float e2[16];
#pragma unroll
    for (int i = 0; i < 4; ++i) {
        const float dh = 0.5f * d[i];
#pragma unroll
        for (int j = 0; j < 4; ++j) e2[i*4+j] = dh * d[j];
    }
    float fv[4];
#pragma unroll
    for (int i = 0; i < 4; ++i) fv[i] = fmaf(d[i], (1.f/3.f), S1[i]);
#pragma unroll
    for (int i = 0; i < 4; ++i) {
#pragma unroll
        for (int j = 0; j < 4; ++j) {
            const float s2 = S2[i*4+j]; const float fi = fv[i];
#pragma unroll
            for (int k = 0; k < 4; ++k)
                S3[(i*4+j)*4+k] = fmaf(s2, d[k], fmaf(fi, e2[j*4+k], S3[(i*4+j)*4+k]));
        }
    }
#pragma unroll
    for (int i = 0; i < 4; ++i)
#pragma unroll
        for (int j = 0; j < 4; ++j) S2[i*4+j] = fmaf(S1[i], d[j], S2[i*4+j] + e2[i*4+j]);
#pragma unroll
    for (int i = 0; i < 4; ++i) S1[i] += d[i];
}

// grid: (4 t-chunks, 64 j, 32 b); block 64 = 1 wave; block owns t-cols [bx*64, bx*64+64).
// Single LDS region: 64 rows x 256 B, XOR-swizzled (slot16 ^= row&7) on BOTH sides.
// sigma occupies shorts [0,96) of each row (k-padded), u occupies [0,128) -- sequential
// phases separated by __syncthreads() (round-4 lesson: compiler may hoist non-self-
// aliasing ds_reads above other lanes' ds_writes without a barrier).
__global__ __launch_bounds__(64, 2) void stem_main(
    const float* __restrict__ x, const int* __restrict__ path,
    const float* __restrict__ wsf, const unsigned short* __restrict__ wsA1,
    const unsigned short* __restrict__ wsA2, float* __restrict__ out)
{
    __shared__ unsigned short sbuf[64 * 128];    // 16384 B
    const int l  = threadIdx.x;                  // lane
    const int t  = blockIdx.x * 64 + l;          // global t for this thread's column
    const int j  = blockIdx.y;
    const int b  = blockIdx.z;
    const float* xb = x + (size_t)b * (3*64*256);

    const int lg = l >> 4;      // lane k-group
    const int li = l & 15;      // m/n index within tile
    char* const myrow = (char*)sbuf + l*256;     // this thread's LDS row
    const int myswz = (l & 7);

    // conv window loads issued early (held in regs; zero-pad in T)
    float xv[9];
#pragma unroll
    for (int ci = 0; ci < 3; ++ci) {
        const float* xr = xb + (ci*64 + j)*256;
        xv[ci*3+0] = (t >= 1)   ? xr[t-1] : 0.f;
        xv[ci*3+1] = xr[t];
        xv[ci*3+2] = (t <= 254) ? xr[t+1] : 0.f;
    }

    // ---- sigma_s (registers) ----
    float sig[84];
#pragma unroll
    for (int i = 0; i < 84; ++i) sig[i] = 0.f;
    {
        float pr0=0.f, pr1=0.f, pr2=0.f, pr3=0.f;
#pragma unroll
        for (int s = 0; s < 5; ++s) {
            const int jp = path[j*5 + s];                 // wave-uniform
            const float p0 = xb[(0*64 + jp)*256 + t];
            const float p1 = xb[(1*64 + jp)*256 + t];
            const float p2 = xb[(2*64 + jp)*256 + t];
            const float p3 = (float)s * 0.25f;
            const float d[4] = { p0-pr0, p1-pr1, p2-pr2, p3-pr3 };
            pr0=p0; pr1=p1; pr2=p2; pr3=p3;
            sig_step(sig, d);
        }
    }
    // pack sigma (84 vals + 12 zero pad -> 96 shorts) to own row, swizzled
    {
        unsigned uu[48];
#pragma unroll
        for (int i = 0; i < 42; ++i) uu[i] = cvtpk(sig[2*i], sig[2*i+1]);
#pragma unroll
        for (int i = 42; i < 48; ++i) uu[i] = 0u;
#pragma unroll
        for (int v = 0; v < 12; ++v) {
            uint32x4 w = { uu[4*v], uu[4*v+1], uu[4*v+2], uu[4*v+3] };
            *(uint32x4*)(myrow + ((v ^ myswz) << 4)) = w;
        }
    }
    __syncthreads();                                      // W->R: sigma_s rows ready

    // ---- GEMM1a: acc += A(h=0) * sigma_s ----
    f32x4 acc[4][4];
#pragma unroll
    for (int a = 0; a < 4; ++a)
#pragma unroll
        for (int c = 0; c < 4; ++c) acc[a][c] = (f32x4){0.f,0.f,0.f,0.f};
    {
#pragma unroll
        for (int s = 0; s < 3; ++s) {
            bf16x8 A0 = *(const bf16x8*)(wsA1 + ((0*3+s)*4+0)*512 + l*8);
            bf16x8 A1 = *(const bf16x8*)(wsA1 + ((0*3+s)*4+1)*512 + l*8);
            bf16x8 A2 = *(const bf16x8*)(wsA1 + ((0*3+s)*4+2)*512 + l*8);
            bf16x8 A3 = *(const bf16x8*)(wsA1 + ((0*3+s)*4+3)*512 + l*8);
#pragma unroll
            for (int tt = 0; tt < 4; ++tt) {
                const int row = tt*16 + li;
                const bf16x8 B = *(const bf16x8*)((const char*)sbuf + row*256 + (((s*4+lg) ^ (li&7)) << 4));
                acc[0][tt] = __builtin_amdgcn_mfma_f32_16x16x32_bf16(A0, B, acc[0][tt], 0, 0, 0);
                acc[1][tt] = __builtin_amdgcn_mfma_f32_16x16x32_bf16(A1, B, acc[1][tt], 0, 0, 0);
                acc[2][tt] = __builtin_amdgcn_mfma_f32_16x16x32_bf16(A2, B, acc[2][tt], 0, 0, 0);
                acc[3][tt] = __builtin_amdgcn_mfma_f32_16x16x32_bf16(A3, B, acc[3][tt], 0, 0, 0);
            }
        }
    }
    __syncthreads();                                      // R->W: done reading sigma_s

    // ---- sigma_t (registers) -> same LDS rows ----
#pragma unroll
    for (int i = 0; i < 84; ++i) sig[i] = 0.f;
    {
        float pr0=0.f, pr1=0.f, pr2=0.f, pr3=0.f;
#pragma unroll
        for (int k = 0; k < 7; ++k) {
            const int idx  = j*7 + k;                     // scrambled temporal window
            const int jsrc = idx & 63;
            const int tl   = idx >> 6;
            const int ts   = min(max(t + tl - 3, 0), 255);
            const float p0 = xb[(0*64 + jsrc)*256 + ts];
            const float p1 = xb[(1*64 + jsrc)*256 + ts];
            const float p2 = xb[(2*64 + jsrc)*256 + ts];
            const float p3 = (float)k * (1.f/6.f);
            const float d[4] = { p0-pr0, p1-pr1, p2-pr2, p3-pr3 };
            pr0=p0; pr1=p1; pr2=p2; pr3=p3;
            sig_step(sig, d);
        }
    }
    {
        unsigned uu[48];
#pragma unroll
        for (int i = 0; i < 42; ++i) uu[i] = cvtpk(sig[2*i], sig[2*i+1]);
#pragma unroll
        for (int i = 42; i < 48; ++i) uu[i] = 0u;
#pragma unroll
        for (int v = 0; v < 12; ++v) {
            uint32x4 w = { uu[4*v], uu[4*v+1], uu[4*v+2], uu[4*v+3] };
            *(uint32x4*)(myrow + ((v ^ myswz) << 4)) = w;
        }
    }
    __syncthreads();                                      // W->R: sigma_t rows ready

    // ---- GEMM1b: acc += A(h=1) * sigma_t ----
    {
#pragma unroll
        for (int s = 0; s < 3; ++s) {
            bf16x8 A0 = *(const bf16x8*)(wsA1 + ((1*3+s)*4+0)*512 + l*8);
            bf16x8 A1 = *(const bf16x8*)(wsA1 + ((1*3+s)*4+1)*512 + l*8);
            bf16x8 A2 = *(const bf16x8*)(wsA1 + ((1*3+s)*4+2)*512 + l*8);
            bf16x8 A3 = *(const bf16x8*)(wsA1 + ((1*3+s)*4+3)*512 + l*8);
#pragma unroll
            for (int tt = 0; tt < 4; ++tt) {
                const int row = tt*16 + li;
                const bf16x8 B = *(const bf16x8*)((const char*)sbuf + row*256 + (((s*4+lg) ^ (li&7)) << 4));
                acc[0][tt] = __builtin_amdgcn_mfma_f32_16x16x32_bf16(A0, B, acc[0][tt], 0, 0, 0);
                acc[1][tt] = __builtin_amdgcn_mfma_f32_16x16x32_bf16(A1, B, acc[1][tt], 0, 0, 0);
                acc[2][tt] = __builtin_amdgcn_mfma_f32_16x16x32_bf16(A2, B, acc[2][tt], 0, 0, 0);
                acc[3][tt] = __builtin_amdgcn_mfma_f32_16x16x32_bf16(A3, B, acc[3][tt], 0, 0, 0);
            }
        }
    }
    __syncthreads();                                      // R->W: done reading sigma_t

    // ---- u assembly: u[t][c<64] = relu(conv_c), u[t][64+o] = relu(ps_o) ----
    // ps epilogue (C/D: col=li -> t, row=lg*4+r -> o); 8B stores stay inside one 16B slot
#pragma unroll
    for (int to = 0; to < 4; ++to) {
        const f32x4 b0 = *(const f32x4*)(wsf + WS_B0 + to*16 + lg*4);
#pragma unroll
        for (int tt = 0; tt < 4; ++tt) {
            const unsigned w0 = cvtpk(fmaxf(acc[to][tt][0] + b0[0], 0.f),
                                      fmaxf(acc[to][tt][1] + b0[1], 0.f));
            const unsigned w1 = cvtpk(fmaxf(acc[to][tt][2] + b0[2], 0.f),
                                      fmaxf(acc[to][tt][3] + b0[3], 0.f));
            uint32x2 w = { w0, w1 };
            const int row = tt*16 + li;
            const int c16 = 8 + to*2 + (lg >> 1);         // 16B slot of byte 128+to*32+lg*8
            *(uint32x2*)((char*)sbuf + row*256 + (((c16 ^ (li&7)) << 4) | ((lg & 1) << 3))) = w;
        }
    }
    // conv half into own row
    {
        unsigned cu[32];
#pragma unroll
        for (int cc = 0; cc < 32; ++cc) {
            float v0 = wsf[WS_BC + 2*cc];
            float v1 = wsf[WS_BC + 2*cc + 1];
#pragma unroll
            for (int i = 0; i < 9; ++i) {
                v0 = fmaf(xv[i], wsf[WS_WC + (2*cc)*9 + i], v0);
                v1 = fmaf(xv[i], wsf[WS_WC + (2*cc+1)*9 + i], v1);
            }
            cu[cc] = cvtpk(fmaxf(v0, 0.f), fmaxf(v1, 0.f));
        }
#pragma unroll
        for (int v = 0; v < 8; ++v) {
            uint32x4 w = { cu[4*v], cu[4*v+1], cu[4*v+2], cu[4*v+3] };
            *(uint32x4*)(myrow + ((v ^ myswz) << 4)) = w;
        }
    }
    __syncthreads();                                      // W->R: u rows ready

    // ---- GEMM2: out = relu(Wf^T u + BF) ----
#pragma unroll
    for (int a = 0; a < 4; ++a)
#pragma unroll
        for (int c = 0; c < 4; ++c) acc[a][c] = (f32x4){0.f,0.f,0.f,0.f};
    {
#pragma unroll
        for (int s = 0; s < 4; ++s) {
            bf16x8 A0 = *(const bf16x8*)(wsA2 + (s*4+0)*512 + l*8);
            bf16x8 A1 = *(const bf16x8*)(wsA2 + (s*4+1)*512 + l*8);
            bf16x8 A2 = *(const bf16x8*)(wsA2 + (s*4+2)*512 + l*8);
            bf16x8 A3 = *(const bf16x8*)(wsA2 + (s*4+3)*512 + l*8);
#pragma unroll
            for (int tt = 0; tt < 4; ++tt) {
                const int row = tt*16 + li;
                const bf16x8 B = *(const bf16x8*)((const char*)sbuf + row*256 + (((s*4+lg) ^ (li&7)) << 4));
                acc[0][tt] = __builtin_amdgcn_mfma_f32_16x16x32_bf16(A0, B, acc[0][tt], 0, 0, 0);
                acc[1][tt] = __builtin_amdgcn_mfma_f32_16x16x32_bf16(A1, B, acc[1][tt], 0, 0, 0);
                acc[2][tt] = __builtin_amdgcn_mfma_f32_16x16x32_bf16(A2, B, acc[2][tt], 0, 0, 0);
                acc[3][tt] = __builtin_amdgcn_mfma_f32_16x16x32_bf16(A3, B, acc[3][tt], 0, 0, 0);
            }
        }
    }

    // ---- final epilogue: add BF, relu, store out[b][o][j][t] ----
#pragma unroll
    for (int to = 0; to < 4; ++to) {
        const f32x4 bf4 = *(const f32x4*)(wsf + WS_BF + to*16 + lg*4);
#pragma unroll
        for (int tt = 0; tt < 4; ++tt) {
            const int tg = blockIdx.x*64 + tt*16 + li;
#pragma unroll
            for (int r = 0; r < 4; ++r) {
                const int o = to*16 + lg*4 + r;
                out[(((size_t)b*64 + o)*64 + j)*256 + tg] = fmaxf(acc[to][tt][r] + bf4[r], 0.f);
            }
        }
    }
}

extern "C" void kernel_launch(void* const* d_in, const int* in_sizes, int n_in,
                              void* d_out, int out_size, void* d_ws, size_t ws_size,
                              hipStream_t stream)
{
    const float* x      = (const float*)d_in[0];
    const int*   path   = (const int*)  d_in[1];
    const float* W_ssig = (const float*)d_in[2];
    const float* b_ssig = (const float*)d_in[3];
    const float* W_tsig = (const float*)d_in[4];
    const float* b_tsig = (const float*)d_in[5];
    const float* W_raw  = (const float*)d_in[6];
    const float* b_raw  = (const float*)d_in[7];
    const float* W_ps   = (const float*)d_in[8];
    const float* b_ps   = (const float*)d_in[9];
    const float* W_fu   = (const float*)d_in[10];
    const float* b_fu   = (const float*)d_in[11];
    const float* g_raw  = (const float*)d_in[12];
    const float* be_raw = (const float*)d_in[13];
    const float* m_raw  = (const float*)d_in[14];
    const float* v_raw  = (const float*)d_in[15];
    const float* g_ps   = (const float*)d_in[16];
    const float* be_ps  = (const float*)d_in[17];
    const float* m_ps   = (const float*)d_in[18];
    const float* v_ps   = (const float*)d_in[19];
    const float* g_fu   = (const float*)d_in[20];
    const float* be_fu  = (const float*)d_in[21];
    const float* m_fu   = (const float*)d_in[22];
    const float* v_fu   = (const float*)d_in[23];
    float* out = (float*)d_out;

    float*          wsf  = (float*)d_ws;
    unsigned short* wsA1 = (unsigned short*)((char*)d_ws + 4096);
    unsigned short* wsA2 = (unsigned short*)((char*)d_ws + 28672);

    stem_prep<<<41, 64, 0, stream>>>(W_ssig, b_ssig, W_tsig, b_tsig, W_raw, b_raw,
                                     W_ps, b_ps, W_fu, b_fu,
                                     g_raw, be_raw, m_raw, v_raw,
                                     g_ps, be_ps, m_ps, v_ps,
                                     g_fu, be_fu, m_fu, v_fu, wsf, wsA1, wsA2);

    dim3 grid(4, 64, 32);   // (t-chunks, J, B)
    stem_main<<<grid, 64, 0, stream>>>(x, path, wsf, wsA1, wsA2, out);
}

// Round 7
// 87.715 us; speedup vs baseline: 30.1300x; 1.0338x over previous
//
#include <hip/hip_runtime.h>
#include <cstdint>

#define EPSF 1e-5f

typedef __attribute__((ext_vector_type(8))) short     bf16x8;
typedef __attribute__((ext_vector_type(4))) float     f32x4;
typedef __attribute__((ext_vector_type(4))) unsigned int uint32x4;
typedef __attribute__((ext_vector_type(2))) unsigned int uint32x2;

// ---- workspace layout ----
// floats (at byte 0): B0[64] @0, BC[64] @64, BF[64] @128, WC[64*9] @192  (ends 768 floats)
#define WS_B0 0
#define WS_BC 64
#define WS_BF 128
#define WS_WC 192
// bf16 A-fragments: wsA1 at byte 4096 (24 frags * 64 lanes * 8 = 12288 ushort)
//                   wsA2 at byte 28672 (16 frags * 64 lanes * 8 =  8192 ushort)

__device__ __forceinline__ unsigned short f2bf(float f) {
    union { float f; unsigned u; } v; v.f = f;
    unsigned r = v.u + 0x7fffu + ((v.u >> 16) & 1u);   // RNE
    return (unsigned short)(r >> 16);
}

// packed f32x2 -> bf16x2 (RNE), single HW instruction on gfx950
__device__ __forceinline__ unsigned cvtpk(float lo, float hi) {
    unsigned r;
    asm("v_cvt_pk_bf16_f32 %0, %1, %2" : "=v"(r) : "v"(lo), "v"(hi));
    return r;
}

// ---------------- prep: fold BNs, collapse W_ps@{W_ssig,W_tsig}, pack MFMA A-frags ----------------
__global__ __launch_bounds__(64) void stem_prep(
    const float* __restrict__ W_ssig, const float* __restrict__ b_ssig,
    const float* __restrict__ W_tsig, const float* __restrict__ b_tsig,
    const float* __restrict__ W_raw,  const float* __restrict__ b_raw,
    const float* __restrict__ W_ps,   const float* __restrict__ b_ps,
    const float* __restrict__ W_fu,   const float* __restrict__ b_fu,
    const float* __restrict__ g_raw, const float* __restrict__ be_raw,
    const float* __restrict__ m_raw, const float* __restrict__ v_raw,
    const float* __restrict__ g_ps,  const float* __restrict__ be_ps,
    const float* __restrict__ m_ps,  const float* __restrict__ v_ps,
    const float* __restrict__ g_fu,  const float* __restrict__ be_fu,
    const float* __restrict__ m_fu,  const float* __restrict__ v_fu,
    float* __restrict__ wsf, unsigned short* __restrict__ wsA1,
    unsigned short* __restrict__ wsA2)
{
    const int l = threadIdx.x;         // 0..63
    const int f = blockIdx.x;
    if (f < 24) {
        // A1 frag f = h*12 + s*4 + to ; element b: W1[k=s*32+8*(l>>4)+b][o=to*16+(l&15)]
        const int h = f / 12, rem = f % 12, s = rem / 4, to = rem % 4;
        const int o = to*16 + (l & 15);
        const float sps = g_ps[o] / sqrtf(v_ps[o] + EPSF);
        const float* wp  = W_ps + o*128 + 64*h;
        const float* wsg = h ? W_tsig : W_ssig;
        for (int b = 0; b < 8; ++b) {
            const int k = s*32 + ((l >> 4) * 8) + b;
            float v = 0.f;
            if (k < 84) {
                float acc = 0.f;
                for (int c = 0; c < 64; ++c) acc = fmaf(wp[c], wsg[c*84 + k], acc);
                v = acc * sps;
            }
            wsA1[f*512 + l*8 + b] = f2bf(v);
        }
    } else if (f < 40) {
        // A2 frag q = s*4+to ; element b: Wf[c=s*32+8*(l>>4)+b][o] = sfu[o]*W_fu[o*128+c]
        const int q = f - 24, s = q / 4, to = q % 4;
        const int o = to*16 + (l & 15);
        const float sfu = g_fu[o] / sqrtf(v_fu[o] + EPSF);
        for (int b = 0; b < 8; ++b) {
            const int c = s*32 + ((l >> 4) * 8) + b;
            wsA2[q*512 + l*8 + b] = f2bf(W_fu[o*128 + c] * sfu);
        }
    } else {
        const int o = l;
        const float sps = g_ps[o] / sqrtf(v_ps[o] + EPSF);
        float acc = b_ps[o] - m_ps[o];
        for (int c = 0; c < 64; ++c) {
            acc = fmaf(W_ps[o*128 + c],      b_ssig[c], acc);
            acc = fmaf(W_ps[o*128 + 64 + c], b_tsig[c], acc);
        }
        wsf[WS_B0 + o] = acc * sps + be_ps[o];
        const float sraw = g_raw[o] / sqrtf(v_raw[o] + EPSF);
        wsf[WS_BC + o] = (b_raw[o] - m_raw[o]) * sraw + be_raw[o];
        const float sfu = g_fu[o] / sqrtf(v_fu[o] + EPSF);
        wsf[WS_BF + o] = (b_fu[o] - m_fu[o]) * sfu + be_fu[o];
        for (int i = 0; i < 9; ++i) wsf[WS_WC + o*9 + i] = W_raw[o*9 + i] * sraw;
    }
}

// one depth-3 signature step; sig = [S1(0..3)|S2(4..19)|S3(20..83)], all static-indexed.
// d[3] is a compile-time literal at every call site (fully unrolled) -> folds.
__device__ __forceinline__ void sig_step(float* __restrict__ sig, const float d[4])
{
    float* S1 = sig; float* S2 = sig + 4; float* S3 = sig + 20;
    float e2[16];
#pragma unroll
    for (int i = 0; i < 4; ++i) {
        const float dh = 0.5f * d[i];
#pragma unroll
        for (int j = 0; j < 4; ++j) e2[i*4+j] = dh * d[j];
    }
    float fv[4];
#pragma unroll
    for (int i = 0; i < 4; ++i) fv[i] = fmaf(d[i], (1.f/3.f), S1[i]);
#pragma unroll
    for (int i = 0; i < 4; ++i) {
#pragma unroll
        for (int j = 0; j < 4; ++j) {
            const float s2 = S2[i*4+j]; const float fi = fv[i];
#pragma unroll
            for (int k = 0; k < 4; ++k)
                S3[(i*4+j)*4+k] = fmaf(s2, d[k], fmaf(fi, e2[j*4+k], S3[(i*4+j)*4+k]));
        }
    }
#pragma unroll
    for (int i = 0; i < 4; ++i)
#pragma unroll
        for (int j = 0; j < 4; ++j) S2[i*4+j] = fmaf(S1[i], d[j], S2[i*4+j] + e2[i*4+j]);
#pragma unroll
    for (int i = 0; i < 4; ++i) S1[i] += d[i];
}

// first step from zero state with d[3]==0: S1=d, S2=e2, S3=d (x) e2 / 3.
// Writes ALL 84 entries (replaces zero-init); compiler folds the d3=0 zeros.
__device__ __forceinline__ void sig_init(float* __restrict__ sig, float d0, float d1, float d2)
{
    const float dd[4] = { d0, d1, d2, 0.f };
#pragma unroll
    for (int i = 0; i < 4; ++i) sig[i] = dd[i];
#pragma unroll
    for (int i = 0; i < 4; ++i) {
        const float dh = 0.5f * dd[i];
#pragma unroll
        for (int j = 0; j < 4; ++j) sig[4 + i*4 + j] = dh * dd[j];
    }
#pragma unroll
    for (int i = 0; i < 4; ++i) {
        const float di3 = dd[i] * (1.f/3.f);
#pragma unroll
        for (int j = 0; j < 4; ++j)
#pragma unroll
            for (int k = 0; k < 4; ++k)
                sig[20 + (i*4+j)*4 + k] = di3 * sig[4 + j*4 + k];
    }
}

// grid: (4 t-chunks, 64 j, 32 b); block 64 = 1 wave; block owns t-cols [bx*64, bx*64+64).
// k-major LDS: slot s (16B per row) at byte s*1024 + row*16; 12 slots = 12288 B peak.
// Writes: v_addr = l*16, slot via offset-immediate -> minimal addr VALU, b128-floor conflicts.
// GEMM2 split into ps-half and conv-half (8 slots each) reusing the same region.
// Explicit __syncthreads() at every LDS W->R / R->W boundary (round-4 lesson).
__global__ __launch_bounds__(64, 3) void stem_main(
    const float* __restrict__ x, const int* __restrict__ path,
    const float* __restrict__ wsf, const unsigned short* __restrict__ wsA1,
    const unsigned short* __restrict__ wsA2, float* __restrict__ out)
{
    __shared__ char sb[12 * 1024];
    const int l  = threadIdx.x;                  // lane
    const int t  = blockIdx.x * 64 + l;          // global t for this thread's column
    const int j  = blockIdx.y;
    const int b  = blockIdx.z;
    const float* xb = x + (size_t)b * (3*64*256);

    const int lg = l >> 4;      // lane k-group
    const int li = l & 15;      // m/n index within tile
    char* const myw = sb + l*16;                 // write base: slot via immediate

    // ---- sigma_s: step-1 specialized, then 4 general steps (d3 = 0.25 literal) ----
    float sig[84];
    {
        int jp = path[j*5 + 0];
        float pr0 = xb[(0*64 + jp)*256 + t];
        float pr1 = xb[(1*64 + jp)*256 + t];
        float pr2 = xb[(2*64 + jp)*256 + t];
        sig_init(sig, pr0, pr1, pr2);
#pragma unroll
        for (int s = 1; s < 5; ++s) {
            jp = path[j*5 + s];
            const float p0 = xb[(0*64 + jp)*256 + t];
            const float p1 = xb[(1*64 + jp)*256 + t];
            const float p2 = xb[(2*64 + jp)*256 + t];
            const float d[4] = { p0-pr0, p1-pr1, p2-pr2, 0.25f };
            pr0=p0; pr1=p1; pr2=p2;
            sig_step(sig, d);
        }
    }
    // pack sigma k-major: slot v holds sig[8v..8v+7] (bf16), rows = lanes
    {
        unsigned uu[48];
#pragma unroll
        for (int i = 0; i < 42; ++i) uu[i] = cvtpk(sig[2*i], sig[2*i+1]);
#pragma unroll
        for (int i = 42; i < 48; ++i) uu[i] = 0u;
#pragma unroll
        for (int v = 0; v < 12; ++v) {
            uint32x4 w = { uu[4*v], uu[4*v+1], uu[4*v+2], uu[4*v+3] };
            *(uint32x4*)(myw + v*1024) = w;
        }
    }
    __syncthreads();                                      // W->R: sigma_s ready

    // ---- GEMM1a: acc = B0 + A(h=0) * sigma_s  (C initialized with folded bias) ----
    f32x4 acc[4][4];
#pragma unroll
    for (int to = 0; to < 4; ++to) {
        const f32x4 b0 = *(const f32x4*)(wsf + WS_B0 + to*16 + lg*4);
#pragma unroll
        for (int tt = 0; tt < 4; ++tt) acc[to][tt] = b0;
    }
    {
#pragma unroll
        for (int s = 0; s < 3; ++s) {
            bf16x8 A0 = *(const bf16x8*)(wsA1 + ((0*3+s)*4+0)*512 + l*8);
            bf16x8 A1 = *(const bf16x8*)(wsA1 + ((0*3+s)*4+1)*512 + l*8);
            bf16x8 A2 = *(const bf16x8*)(wsA1 + ((0*3+s)*4+2)*512 + l*8);
            bf16x8 A3 = *(const bf16x8*)(wsA1 + ((0*3+s)*4+3)*512 + l*8);
#pragma unroll
            for (int tt = 0; tt < 4; ++tt) {
                const bf16x8 B = *(const bf16x8*)(sb + (s*4+lg)*1024 + (tt*16+li)*16);
                acc[0][tt] = __builtin_amdgcn_mfma_f32_16x16x32_bf16(A0, B, acc[0][tt], 0, 0, 0);
                acc[1][tt] = __builtin_amdgcn_mfma_f32_16x16x32_bf16(A1, B, acc[1][tt], 0, 0, 0);
                acc[2][tt] = __builtin_amdgcn_mfma_f32_16x16x32_bf16(A2, B, acc[2][tt], 0, 0, 0);
                acc[3][tt] = __builtin_amdgcn_mfma_f32_16x16x32_bf16(A3, B, acc[3][tt], 0, 0, 0);
            }
        }
    }
    __syncthreads();                                      // R->W: done reading sigma_s

    // ---- sigma_t: scrambled window; step-1 specialized, 6 general steps (d3 = 1/6) ----
    {
        int idx  = j*7;
        int jsrc = idx & 63, tl = idx >> 6;
        int ts   = min(max(t + tl - 3, 0), 255);
        float pr0 = xb[(0*64 + jsrc)*256 + ts];
        float pr1 = xb[(1*64 + jsrc)*256 + ts];
        float pr2 = xb[(2*64 + jsrc)*256 + ts];
        sig_init(sig, pr0, pr1, pr2);
#pragma unroll
        for (int k = 1; k < 7; ++k) {
            idx = j*7 + k; jsrc = idx & 63; tl = idx >> 6;
            ts = min(max(t + tl - 3, 0), 255);
            const float p0 = xb[(0*64 + jsrc)*256 + ts];
            const float p1 = xb[(1*64 + jsrc)*256 + ts];
            const float p2 = xb[(2*64 + jsrc)*256 + ts];
            const float d[4] = { p0-pr0, p1-pr1, p2-pr2, (1.f/6.f) };
            pr0=p0; pr1=p1; pr2=p2;
            sig_step(sig, d);
        }
    }
    {
        unsigned uu[48];
#pragma unroll
        for (int i = 0; i < 42; ++i) uu[i] = cvtpk(sig[2*i], sig[2*i+1]);
#pragma unroll
        for (int i = 42; i < 48; ++i) uu[i] = 0u;
#pragma unroll
        for (int v = 0; v < 12; ++v) {
            uint32x4 w = { uu[4*v], uu[4*v+1], uu[4*v+2], uu[4*v+3] };
            *(uint32x4*)(myw + v*1024) = w;
        }
    }
    __syncthreads();                                      // W->R: sigma_t ready

    // ---- GEMM1b: acc += A(h=1) * sigma_t ----
    {
#pragma unroll
        for (int s = 0; s < 3; ++s) {
            bf16x8 A0 = *(const bf16x8*)(wsA1 + ((1*3+s)*4+0)*512 + l*8);
            bf16x8 A1 = *(const bf16x8*)(wsA1 + ((1*3+s)*4+1)*512 + l*8);
            bf16x8 A2 = *(const bf16x8*)(wsA1 + ((1*3+s)*4+2)*512 + l*8);
            bf16x8 A3 = *(const bf16x8*)(wsA1 + ((1*3+s)*4+3)*512 + l*8);
#pragma unroll
            for (int tt = 0; tt < 4; ++tt) {
                const bf16x8 B = *(const bf16x8*)(sb + (s*4+lg)*1024 + (tt*16+li)*16);
                acc[0][tt] = __builtin_amdgcn_mfma_f32_16x16x32_bf16(A0, B, acc[0][tt], 0, 0, 0);
                acc[1][tt] = __builtin_amdgcn_mfma_f32_16x16x32_bf16(A1, B, acc[1][tt], 0, 0, 0);
                acc[2][tt] = __builtin_amdgcn_mfma_f32_16x16x32_bf16(A2, B, acc[2][tt], 0, 0, 0);
                acc[3][tt] = __builtin_amdgcn_mfma_f32_16x16x32_bf16(A3, B, acc[3][tt], 0, 0, 0);
            }
        }
    }
    __syncthreads();                                      // R->W: done reading sigma_t

    // ---- ps pack: u_ps[row][o] = bf16(relu(acc)), k-major (slot = o>>3) ----
    // lane holds o = to*16+lg*4+r, row = tt*16+li -> 8B store at slot (to*2+(lg>>1)),
    // byte-in-line (lg&1)*8.
#pragma unroll
    for (int to = 0; to < 4; ++to) {
#pragma unroll
        for (int tt = 0; tt < 4; ++tt) {
            const unsigned w0 = cvtpk(fmaxf(acc[to][tt][0], 0.f), fmaxf(acc[to][tt][1], 0.f));
            const unsigned w1 = cvtpk(fmaxf(acc[to][tt][2], 0.f), fmaxf(acc[to][tt][3], 0.f));
            uint32x2 w = { w0, w1 };
            *(uint32x2*)(sb + (to*2+(lg>>1))*1024 + (tt*16+li)*16 + ((lg&1)<<3)) = w;
        }
    }
    __syncthreads();                                      // W->R: u_ps ready

    // conv window loads (late -> keeps sigma-phase register pressure low; hidden under G2ps)
    float xv[9];
#pragma unroll
    for (int ci = 0; ci < 3; ++ci) {
        const float* xr = xb + (ci*64 + j)*256;
        xv[ci*3+0] = (t >= 1)   ? xr[t-1] : 0.f;
        xv[ci*3+1] = xr[t];
        xv[ci*3+2] = (t <= 254) ? xr[t+1] : 0.f;
    }

    // ---- GEMM2-ps: acc = BF + Wf_hi^T u_ps  (A2 frags q = 8..15) ----
#pragma unroll
    for (int to = 0; to < 4; ++to) {
        const f32x4 bf4 = *(const f32x4*)(wsf + WS_BF + to*16 + lg*4);
#pragma unroll
        for (int tt = 0; tt < 4; ++tt) acc[to][tt] = bf4;
    }
    {
#pragma unroll
        for (int s = 0; s < 2; ++s) {
            bf16x8 A0 = *(const bf16x8*)(wsA2 + ((s+2)*4+0)*512 + l*8);
            bf16x8 A1 = *(const bf16x8*)(wsA2 + ((s+2)*4+1)*512 + l*8);
            bf16x8 A2 = *(const bf16x8*)(wsA2 + ((s+2)*4+2)*512 + l*8);
            bf16x8 A3 = *(const bf16x8*)(wsA2 + ((s+2)*4+3)*512 + l*8);
#pragma unroll
            for (int tt = 0; tt < 4; ++tt) {
                const bf16x8 B = *(const bf16x8*)(sb + (s*4+lg)*1024 + (tt*16+li)*16);
                acc[0][tt] = __builtin_amdgcn_mfma_f32_16x16x32_bf16(A0, B, acc[0][tt], 0, 0, 0);
                acc[1][tt] = __builtin_amdgcn_mfma_f32_16x16x32_bf16(A1, B, acc[1][tt], 0, 0, 0);
                acc[2][tt] = __builtin_amdgcn_mfma_f32_16x16x32_bf16(A2, B, acc[2][tt], 0, 0, 0);
                acc[3][tt] = __builtin_amdgcn_mfma_f32_16x16x32_bf16(A3, B, acc[3][tt], 0, 0, 0);
            }
        }
    }
    __syncthreads();                                      // R->W: done reading u_ps

    // ---- conv: u_conv[row][c] = bf16(relu(conv_c)), own row, k-major ----
    {
        unsigned cu[32];
#pragma unroll
        for (int cc = 0; cc < 32; ++cc) {
            float v0 = wsf[WS_BC + 2*cc];
            float v1 = wsf[WS_BC + 2*cc + 1];
#pragma unroll
            for (int i = 0; i < 9; ++i) {
                v0 = fmaf(xv[i], wsf[WS_WC + (2*cc)*9 + i], v0);
                v1 = fmaf(xv[i], wsf[WS_WC + (2*cc+1)*9 + i], v1);
            }
            cu[cc] = cvtpk(fmaxf(v0, 0.f), fmaxf(v1, 0.f));
        }
#pragma unroll
        for (int v = 0; v < 8; ++v) {
            uint32x4 w = { cu[4*v], cu[4*v+1], cu[4*v+2], cu[4*v+3] };
            *(uint32x4*)(myw + v*1024) = w;
        }
    }
    __syncthreads();                                      // W->R: u_conv ready

    // ---- GEMM2-conv: acc += Wf_lo^T u_conv  (A2 frags q = 0..7) ----
    {
#pragma unroll
        for (int s = 0; s < 2; ++s) {
            bf16x8 A0 = *(const bf16x8*)(wsA2 + (s*4+0)*512 + l*8);
            bf16x8 A1 = *(const bf16x8*)(wsA2 + (s*4+1)*512 + l*8);
            bf16x8 A2 = *(const bf16x8*)(wsA2 + (s*4+2)*512 + l*8);
            bf16x8 A3 = *(const bf16x8*)(wsA2 + (s*4+3)*512 + l*8);
#pragma unroll
            for (int tt = 0; tt < 4; ++tt) {
                const bf16x8 B = *(const bf16x8*)(sb + (s*4+lg)*1024 + (tt*16+li)*16);
                acc[0][tt] = __builtin_amdgcn_mfma_f32_16x16x32_bf16(A0, B, acc[0][tt], 0, 0, 0);
                acc[1][tt] = __builtin_amdgcn_mfma_f32_16x16x32_bf16(A1, B, acc[1][tt], 0, 0, 0);
                acc[2][tt] = __builtin_amdgcn_mfma_f32_16x16x32_bf16(A2, B, acc[2][tt], 0, 0, 0);
                acc[3][tt] = __builtin_amdgcn_mfma_f32_16x16x32_bf16(A3, B, acc[3][tt], 0, 0, 0);
            }
        }
    }

    // ---- final epilogue: relu (bias already in C-init), store out[b][o][j][t] ----
#pragma unroll
    for (int to = 0; to < 4; ++to) {
#pragma unroll
        for (int tt = 0; tt < 4; ++tt) {
            const int tg = blockIdx.x*64 + tt*16 + li;
#pragma unroll
            for (int r = 0; r < 4; ++r) {
                const int o = to*16 + lg*4 + r;
                out[(((size_t)b*64 + o)*64 + j)*256 + tg] = fmaxf(acc[to][tt][r], 0.f);
            }
        }
    }
}

extern "C" void kernel_launch(void* const* d_in, const int* in_sizes, int n_in,
                              void* d_out, int out_size, void* d_ws, size_t ws_size,
                              hipStream_t stream)
{
    const float* x      = (const float*)d_in[0];
    const int*   path   = (const int*)  d_in[1];
    const float* W_ssig = (const float*)d_in[2];
    const float* b_ssig = (const float*)d_in[3];
    const float* W_tsig = (const float*)d_in[4];
    const float* b_tsig = (const float*)d_in[5];
    const float* W_raw  = (const float*)d_in[6];
    const float* b_raw  = (const float*)d_in[7];
    const float* W_ps   = (const float*)d_in[8];
    const float* b_ps   = (const float*)d_in[9];
    const float* W_fu   = (const float*)d_in[10];
    const float* b_fu   = (const float*)d_in[11];
    const float* g_raw  = (const float*)d_in[12];
    const float* be_raw = (const float*)d_in[13];
    const float* m_raw  = (const float*)d_in[14];
    const float* v_raw  = (const float*)d_in[15];
    const float* g_ps   = (const float*)d_in[16];
    const float* be_ps  = (const float*)d_in[17];
    const float* m_ps   = (const float*)d_in[18];
    const float* v_ps   = (const float*)d_in[19];
    const float* g_fu   = (const float*)d_in[20];
    const float* be_fu  = (const float*)d_in[21];
    const float* m_fu   = (const float*)d_in[22];
    const float* v_fu   = (const float*)d_in[23];
    float* out = (float*)d_out;

    float*          wsf  = (float*)d_ws;
    unsigned short* wsA1 = (unsigned short*)((char*)d_ws + 4096);
    unsigned short* wsA2 = (unsigned short*)((char*)d_ws + 28672);

    stem_prep<<<41, 64, 0, stream>>>(W_ssig, b_ssig, W_tsig, b_tsig, W_raw, b_raw,
                                     W_ps, b_ps, W_fu, b_fu,
                                     g_raw, be_raw, m_raw, v_raw,
                                     g_ps, be_ps, m_ps, v_ps,
                                     g_fu, be_fu, m_fu, v_fu, wsf, wsA1, wsA2);

    dim3 grid(4, 64, 32);   // (t-chunks, J, B)
    stem_main<<<grid, 64, 0, stream>>>(x, path, wsf, wsA1, wsA2, out);
}

// Round 8
// 77.362 us; speedup vs baseline: 34.1619x; 1.1338x over previous
//
#include <hip/hip_runtime.h>
#include <cstdint>

#define EPSF 1e-5f

typedef __attribute__((ext_vector_type(8))) short     bf16x8;
typedef __attribute__((ext_vector_type(4))) float     f32x4;
typedef __attribute__((ext_vector_type(4))) unsigned int uint32x4;
typedef __attribute__((ext_vector_type(2))) unsigned int uint32x2;

// ---- workspace layout ----
// floats (at byte 0): B0[64] @0, BC[64] @64, BF[64] @128, WC[64*9] @192  (ends 768 floats)
#define WS_B0 0
#define WS_BC 64
#define WS_BF 128
#define WS_WC 192
// bf16 A-fragments: wsA1 at byte 4096 (24 frags * 64 lanes * 8 = 12288 ushort)
//                   wsA2 at byte 28672 (16 frags * 64 lanes * 8 =  8192 ushort)

__device__ __forceinline__ unsigned short f2bf(float f) {
    union { float f; unsigned u; } v; v.f = f;
    unsigned r = v.u + 0x7fffu + ((v.u >> 16) & 1u);   // RNE
    return (unsigned short)(r >> 16);
}

// packed f32x2 -> bf16x2 (RNE), single HW instruction on gfx950
__device__ __forceinline__ unsigned cvtpk(float lo, float hi) {
    unsigned r;
    asm("v_cvt_pk_bf16_f32 %0, %1, %2" : "=v"(r) : "v"(lo), "v"(hi));
    return r;
}

// ---------------- prep: fold BNs, collapse W_ps@{W_ssig,W_tsig}, pack MFMA A-frags ----------------
__global__ __launch_bounds__(64) void stem_prep(
    const float* __restrict__ W_ssig, const float* __restrict__ b_ssig,
    const float* __restrict__ W_tsig, const float* __restrict__ b_tsig,
    const float* __restrict__ W_raw,  const float* __restrict__ b_raw,
    const float* __restrict__ W_ps,   const float* __restrict__ b_ps,
    const float* __restrict__ W_fu,   const float* __restrict__ b_fu,
    const float* __restrict__ g_raw, const float* __restrict__ be_raw,
    const float* __restrict__ m_raw, const float* __restrict__ v_raw,
    const float* __restrict__ g_ps,  const float* __restrict__ be_ps,
    const float* __restrict__ m_ps,  const float* __restrict__ v_ps,
    const float* __restrict__ g_fu,  const float* __restrict__ be_fu,
    const float* __restrict__ m_fu,  const float* __restrict__ v_fu,
    float* __restrict__ wsf, unsigned short* __restrict__ wsA1,
    unsigned short* __restrict__ wsA2)
{
    const int l = threadIdx.x;         // 0..63
    const int f = blockIdx.x;
    if (f < 24) {
        // A1 frag f = h*12 + s*4 + to ; element b: W1[k=s*32+8*(l>>4)+b][o=to*16+(l&15)]
        const int h = f / 12, rem = f % 12, s = rem / 4, to = rem % 4;
        const int o = to*16 + (l & 15);
        const float sps = g_ps[o] / sqrtf(v_ps[o] + EPSF);
        const float* wp  = W_ps + o*128 + 64*h;
        const float* wsg = h ? W_tsig : W_ssig;
        for (int b = 0; b < 8; ++b) {
            const int k = s*32 + ((l >> 4) * 8) + b;
            float v = 0.f;
            if (k < 84) {
                float acc = 0.f;
                for (int c = 0; c < 64; ++c) acc = fmaf(wp[c], wsg[c*84 + k], acc);
                v = acc * sps;
            }
            wsA1[f*512 + l*8 + b] = f2bf(v);
        }
    } else if (f < 40) {
        // A2 frag q = s*4+to ; element b: Wf[c=s*32+8*(l>>4)+b][o] = sfu[o]*W_fu[o*128+c]
        const int q = f - 24, s = q / 4, to = q % 4;
        const int o = to*16 + (l & 15);
        const float sfu = g_fu[o] / sqrtf(v_fu[o] + EPSF);
        for (int b = 0; b < 8; ++b) {
            const int c = s*32 + ((l >> 4) * 8) + b;
            wsA2[q*512 + l*8 + b] = f2bf(W_fu[o*128 + c] * sfu);
        }
    } else {
        const int o = l;
        const float sps = g_ps[o] / sqrtf(v_ps[o] + EPSF);
        float acc = b_ps[o] - m_ps[o];
        for (int c = 0; c < 64; ++c) {
            acc = fmaf(W_ps[o*128 + c],      b_ssig[c], acc);
            acc = fmaf(W_ps[o*128 + 64 + c], b_tsig[c], acc);
        }
        wsf[WS_B0 + o] = acc * sps + be_ps[o];
        const float sraw = g_raw[o] / sqrtf(v_raw[o] + EPSF);
        wsf[WS_BC + o] = (b_raw[o] - m_raw[o]) * sraw + be_raw[o];
        const float sfu = g_fu[o] / sqrtf(v_fu[o] + EPSF);
        wsf[WS_BF + o] = (b_fu[o] - m_fu[o]) * sfu + be_fu[o];
        for (int i = 0; i < 9; ++i) wsf[WS_WC + o*9 + i] = W_raw[o*9 + i] * sraw;
    }
}

// one depth-3 signature step; sig = [S1(0..3)|S2(4..19)|S3(20..83)], all static-indexed.
// d[3] is a compile-time literal at every call site (fully unrolled) -> folds.
__device__ __forceinline__ void sig_step(float* __restrict__ sig, const float d[4])
{
    float* S1 = sig; float* S2 = sig + 4; float* S3 = sig + 20;
    float e2[16];
#pragma unroll
    for (int i = 0; i < 4; ++i) {
        const float dh = 0.5f * d[i];
#pragma unroll
        for (int j = 0; j < 4; ++j) e2[i*4+j] = dh * d[j];
    }
    float fv[4];
#pragma unroll
    for (int i = 0; i < 4; ++i) fv[i] = fmaf(d[i], (1.f/3.f), S1[i]);
#pragma unroll
    for (int i = 0; i < 4; ++i) {
#pragma unroll
        for (int j = 0; j < 4; ++j) {
            const float s2 = S2[i*4+j]; const float fi = fv[i];
#pragma unroll
            for (int k = 0; k < 4; ++k)
                S3[(i*4+j)*4+k] = fmaf(s2, d[k], fmaf(fi, e2[j*4+k], S3[(i*4+j)*4+k]));
        }
    }
#pragma unroll
    for (int i = 0; i < 4; ++i)
#pragma unroll
        for (int j = 0; j < 4; ++j) S2[i*4+j] = fmaf(S1[i], d[j], S2[i*4+j] + e2[i*4+j]);
#pragma unroll
    for (int i = 0; i < 4; ++i) S1[i] += d[i];
}

// first step from zero state with d[3]==0: S1=d, S2=e2, S3=d (x) e2 / 3.
__device__ __forceinline__ void sig_init(float* __restrict__ sig, float d0, float d1, float d2)
{
    const float dd[4] = { d0, d1, d2, 0.f };
#pragma unroll
    for (int i = 0; i < 4; ++i) sig[i] = dd[i];
#pragma unroll
    for (int i = 0; i < 4; ++i) {
        const float dh = 0.5f * dd[i];
#pragma unroll
        for (int j = 0; j < 4; ++j) sig[4 + i*4 + j] = dh * dd[j];
    }
#pragma unroll
    for (int i = 0; i < 4; ++i) {
        const float di3 = dd[i] * (1.f/3.f);
#pragma unroll
        for (int j = 0; j < 4; ++j)
#pragma unroll
            for (int k = 0; k < 4; ++k)
                sig[20 + (i*4+j)*4 + k] = di3 * sig[4 + j*4 + k];
    }
}

// grid: (4 t-chunks, 64 j, 32 b); block 64 = 1 wave; block owns t-cols [bx*64, bx*64+64).
// k-major LDS: slot s (16B per row) at byte s*1024 + row*16; 12 slots = 12288 B.
// PHASE ORDER avoids sig[84](f32) x acc(64 AGPR) live overlap (round-7 spill):
//   sigma_s -> LDS; sigma_t -> 42 packed u32 REGS; GEMM1a; dump sigma_t -> LDS; GEMM1b.
// Explicit __syncthreads() at every LDS W->R / R->W boundary (round-4 lesson).
__global__ __launch_bounds__(64, 3) void stem_main(
    const float* __restrict__ x, const int* __restrict__ path,
    const float* __restrict__ wsf, const unsigned short* __restrict__ wsA1,
    const unsigned short* __restrict__ wsA2, float* __restrict__ out)
{
    __shared__ char sb[12 * 1024];
    const int l  = threadIdx.x;                  // lane
    const int t  = blockIdx.x * 64 + l;          // global t for this thread's column
    const int j  = blockIdx.y;
    const int b  = blockIdx.z;
    const float* xb = x + (size_t)b * (3*64*256);

    const int lg = l >> 4;      // lane k-group
    const int li = l & 15;      // m/n index within tile
    char* const myw = sb + l*16;                 // write base: slot via immediate

    // ---- sigma_s: step-1 specialized, then 4 general steps (d3 = 0.25 literal) ----
    float sig[84];
    {
        int jp = path[j*5 + 0];
        float pr0 = xb[(0*64 + jp)*256 + t];
        float pr1 = xb[(1*64 + jp)*256 + t];
        float pr2 = xb[(2*64 + jp)*256 + t];
        sig_init(sig, pr0, pr1, pr2);
#pragma unroll
        for (int s = 1; s < 5; ++s) {
            jp = path[j*5 + s];
            const float p0 = xb[(0*64 + jp)*256 + t];
            const float p1 = xb[(1*64 + jp)*256 + t];
            const float p2 = xb[(2*64 + jp)*256 + t];
            const float d[4] = { p0-pr0, p1-pr1, p2-pr2, 0.25f };
            pr0=p0; pr1=p1; pr2=p2;
            sig_step(sig, d);
        }
    }
    // pack sigma_s k-major to LDS: slot v holds sig[8v..8v+7] (bf16), rows = lanes
    {
        unsigned uu[48];
#pragma unroll
        for (int i = 0; i < 42; ++i) uu[i] = cvtpk(sig[2*i], sig[2*i+1]);
#pragma unroll
        for (int i = 42; i < 48; ++i) uu[i] = 0u;
#pragma unroll
        for (int v = 0; v < 12; ++v) {
            uint32x4 w = { uu[4*v], uu[4*v+1], uu[4*v+2], uu[4*v+3] };
            *(uint32x4*)(myw + v*1024) = w;
        }
    }
    __syncthreads();                                      // W->R: sigma_s ready

    // ---- sigma_t NOW (before acc is born): scrambled window; result packed to regs ----
    unsigned uuT[48];
    {
        int idx  = j*7;
        int jsrc = idx & 63, tl = idx >> 6;
        int ts   = min(max(t + tl - 3, 0), 255);
        float pr0 = xb[(0*64 + jsrc)*256 + ts];
        float pr1 = xb[(1*64 + jsrc)*256 + ts];
        float pr2 = xb[(2*64 + jsrc)*256 + ts];
        sig_init(sig, pr0, pr1, pr2);
#pragma unroll
        for (int k = 1; k < 7; ++k) {
            idx = j*7 + k; jsrc = idx & 63; tl = idx >> 6;
            ts = min(max(t + tl - 3, 0), 255);
            const float p0 = xb[(0*64 + jsrc)*256 + ts];
            const float p1 = xb[(1*64 + jsrc)*256 + ts];
            const float p2 = xb[(2*64 + jsrc)*256 + ts];
            const float d[4] = { p0-pr0, p1-pr1, p2-pr2, (1.f/6.f) };
            pr0=p0; pr1=p1; pr2=p2;
            sig_step(sig, d);
        }
#pragma unroll
        for (int i = 0; i < 42; ++i) uuT[i] = cvtpk(sig[2*i], sig[2*i+1]);
#pragma unroll
        for (int i = 42; i < 48; ++i) uuT[i] = 0u;
    }
    // sig (f32) is DEAD here -> acc can use the freed registers

    // ---- GEMM1a: acc = B0 + A(h=0) * sigma_s ----
    f32x4 acc[4][4];
#pragma unroll
    for (int to = 0; to < 4; ++to) {
        const f32x4 b0 = *(const f32x4*)(wsf + WS_B0 + to*16 + lg*4);
#pragma unroll
        for (int tt = 0; tt < 4; ++tt) acc[to][tt] = b0;
    }
    {
#pragma unroll
        for (int s = 0; s < 3; ++s) {
            bf16x8 A0 = *(const bf16x8*)(wsA1 + ((0*3+s)*4+0)*512 + l*8);
            bf16x8 A1 = *(const bf16x8*)(wsA1 + ((0*3+s)*4+1)*512 + l*8);
            bf16x8 A2 = *(const bf16x8*)(wsA1 + ((0*3+s)*4+2)*512 + l*8);
            bf16x8 A3 = *(const bf16x8*)(wsA1 + ((0*3+s)*4+3)*512 + l*8);
#pragma unroll
            for (int tt = 0; tt < 4; ++tt) {
                const bf16x8 B = *(const bf16x8*)(sb + (s*4+lg)*1024 + (tt*16+li)*16);
                acc[0][tt] = __builtin_amdgcn_mfma_f32_16x16x32_bf16(A0, B, acc[0][tt], 0, 0, 0);
                acc[1][tt] = __builtin_amdgcn_mfma_f32_16x16x32_bf16(A1, B, acc[1][tt], 0, 0, 0);
                acc[2][tt] = __builtin_amdgcn_mfma_f32_16x16x32_bf16(A2, B, acc[2][tt], 0, 0, 0);
                acc[3][tt] = __builtin_amdgcn_mfma_f32_16x16x32_bf16(A3, B, acc[3][tt], 0, 0, 0);
            }
        }
    }
    __syncthreads();                                      // R->W: done reading sigma_s

    // dump packed sigma_t regs -> LDS
    {
#pragma unroll
        for (int v = 0; v < 12; ++v) {
            uint32x4 w = { uuT[4*v], uuT[4*v+1], uuT[4*v+2], uuT[4*v+3] };
            *(uint32x4*)(myw + v*1024) = w;
        }
    }
    __syncthreads();                                      // W->R: sigma_t ready

    // conv window loads issued here (HBM latency hides under GEMM1b + ps pack)
    float xv[9];
#pragma unroll
    for (int ci = 0; ci < 3; ++ci) {
        const float* xr = xb + (ci*64 + j)*256;
        xv[ci*3+0] = (t >= 1)   ? xr[t-1] : 0.f;
        xv[ci*3+1] = xr[t];
        xv[ci*3+2] = (t <= 254) ? xr[t+1] : 0.f;
    }

    // ---- GEMM1b: acc += A(h=1) * sigma_t ----
    {
#pragma unroll
        for (int s = 0; s < 3; ++s) {
            bf16x8 A0 = *(const bf16x8*)(wsA1 + ((1*3+s)*4+0)*512 + l*8);
            bf16x8 A1 = *(const bf16x8*)(wsA1 + ((1*3+s)*4+1)*512 + l*8);
            bf16x8 A2 = *(const bf16x8*)(wsA1 + ((1*3+s)*4+2)*512 + l*8);
            bf16x8 A3 = *(const bf16x8*)(wsA1 + ((1*3+s)*4+3)*512 + l*8);
#pragma unroll
            for (int tt = 0; tt < 4; ++tt) {
                const bf16x8 B = *(const bf16x8*)(sb + (s*4+lg)*1024 + (tt*16+li)*16);
                acc[0][tt] = __builtin_amdgcn_mfma_f32_16x16x32_bf16(A0, B, acc[0][tt], 0, 0, 0);
                acc[1][tt] = __builtin_amdgcn_mfma_f32_16x16x32_bf16(A1, B, acc[1][tt], 0, 0, 0);
                acc[2][tt] = __builtin_amdgcn_mfma_f32_16x16x32_bf16(A2, B, acc[2][tt], 0, 0, 0);
                acc[3][tt] = __builtin_amdgcn_mfma_f32_16x16x32_bf16(A3, B, acc[3][tt], 0, 0, 0);
            }
        }
    }
    __syncthreads();                                      // R->W: done reading sigma_t

    // ---- ps pack: u_ps[row][o] = bf16(relu(acc)), k-major (slot = o>>3) ----
#pragma unroll
    for (int to = 0; to < 4; ++to) {
#pragma unroll
        for (int tt = 0; tt < 4; ++tt) {
            const unsigned w0 = cvtpk(fmaxf(acc[to][tt][0], 0.f), fmaxf(acc[to][tt][1], 0.f));
            const unsigned w1 = cvtpk(fmaxf(acc[to][tt][2], 0.f), fmaxf(acc[to][tt][3], 0.f));
            uint32x2 w = { w0, w1 };
            *(uint32x2*)(sb + (to*2+(lg>>1))*1024 + (tt*16+li)*16 + ((lg&1)<<3)) = w;
        }
    }

    // ---- conv into cu regs (VALU; no LDS) while ps stores land ----
    unsigned cu[32];
#pragma unroll
    for (int cc = 0; cc < 32; ++cc) {
        float v0 = wsf[WS_BC + 2*cc];
        float v1 = wsf[WS_BC + 2*cc + 1];
#pragma unroll
        for (int i = 0; i < 9; ++i) {
            v0 = fmaf(xv[i], wsf[WS_WC + (2*cc)*9 + i], v0);
            v1 = fmaf(xv[i], wsf[WS_WC + (2*cc+1)*9 + i], v1);
        }
        cu[cc] = cvtpk(fmaxf(v0, 0.f), fmaxf(v1, 0.f));
    }
    __syncthreads();                                      // W->R: u_ps ready

    // ---- GEMM2-ps: acc = BF + Wf_hi^T u_ps  (A2 frags q = 8..15) ----
#pragma unroll
    for (int to = 0; to < 4; ++to) {
        const f32x4 bf4 = *(const f32x4*)(wsf + WS_BF + to*16 + lg*4);
#pragma unroll
        for (int tt = 0; tt < 4; ++tt) acc[to][tt] = bf4;
    }
    {
#pragma unroll
        for (int s = 0; s < 2; ++s) {
            bf16x8 A0 = *(const bf16x8*)(wsA2 + ((s+2)*4+0)*512 + l*8);
            bf16x8 A1 = *(const bf16x8*)(wsA2 + ((s+2)*4+1)*512 + l*8);
            bf16x8 A2 = *(const bf16x8*)(wsA2 + ((s+2)*4+2)*512 + l*8);
            bf16x8 A3 = *(const bf16x8*)(wsA2 + ((s+2)*4+3)*512 + l*8);
#pragma unroll
            for (int tt = 0; tt < 4; ++tt) {
                const bf16x8 B = *(const bf16x8*)(sb + (s*4+lg)*1024 + (tt*16+li)*16);
                acc[0][tt] = __builtin_amdgcn_mfma_f32_16x16x32_bf16(A0, B, acc[0][tt], 0, 0, 0);
                acc[1][tt] = __builtin_amdgcn_mfma_f32_16x16x32_bf16(A1, B, acc[1][tt], 0, 0, 0);
                acc[2][tt] = __builtin_amdgcn_mfma_f32_16x16x32_bf16(A2, B, acc[2][tt], 0, 0, 0);
                acc[3][tt] = __builtin_amdgcn_mfma_f32_16x16x32_bf16(A3, B, acc[3][tt], 0, 0, 0);
            }
        }
    }
    __syncthreads();                                      // R->W: done reading u_ps

    // ---- conv store: u_conv[row][c], own row, k-major ----
    {
#pragma unroll
        for (int v = 0; v < 8; ++v) {
            uint32x4 w = { cu[4*v], cu[4*v+1], cu[4*v+2], cu[4*v+3] };
            *(uint32x4*)(myw + v*1024) = w;
        }
    }
    __syncthreads();                                      // W->R: u_conv ready

    // ---- GEMM2-conv: acc += Wf_lo^T u_conv  (A2 frags q = 0..7) ----
    {
#pragma unroll
        for (int s = 0; s < 2; ++s) {
            bf16x8 A0 = *(const bf16x8*)(wsA2 + (s*4+0)*512 + l*8);
            bf16x8 A1 = *(const bf16x8*)(wsA2 + (s*4+1)*512 + l*8);
            bf16x8 A2 = *(const bf16x8*)(wsA2 + (s*4+2)*512 + l*8);
            bf16x8 A3 = *(const bf16x8*)(wsA2 + (s*4+3)*512 + l*8);
#pragma unroll
            for (int tt = 0; tt < 4; ++tt) {
                const bf16x8 B = *(const bf16x8*)(sb + (s*4+lg)*1024 + (tt*16+li)*16);
                acc[0][tt] = __builtin_amdgcn_mfma_f32_16x16x32_bf16(A0, B, acc[0][tt], 0, 0, 0);
                acc[1][tt] = __builtin_amdgcn_mfma_f32_16x16x32_bf16(A1, B, acc[1][tt], 0, 0, 0);
                acc[2][tt] = __builtin_amdgcn_mfma_f32_16x16x32_bf16(A2, B, acc[2][tt], 0, 0, 0);
                acc[3][tt] = __builtin_amdgcn_mfma_f32_16x16x32_bf16(A3, B, acc[3][tt], 0, 0, 0);
            }
        }
    }

    // ---- final epilogue: relu (bias already in C-init), store out[b][o][j][t] ----
#pragma unroll
    for (int to = 0; to < 4; ++to) {
#pragma unroll
        for (int tt = 0; tt < 4; ++tt) {
            const int tg = blockIdx.x*64 + tt*16 + li;
#pragma unroll
            for (int r = 0; r < 4; ++r) {
                const int o = to*16 + lg*4 + r;
                out[(((size_t)b*64 + o)*64 + j)*256 + tg] = fmaxf(acc[to][tt][r], 0.f);
            }
        }
    }
}

extern "C" void kernel_launch(void* const* d_in, const int* in_sizes, int n_in,
                              void* d_out, int out_size, void* d_ws, size_t ws_size,
                              hipStream_t stream)
{
    const float* x      = (const float*)d_in[0];
    const int*   path   = (const int*)  d_in[1];
    const float* W_ssig = (const float*)d_in[2];
    const float* b_ssig = (const float*)d_in[3];
    const float* W_tsig = (const float*)d_in[4];
    const float* b_tsig = (const float*)d_in[5];
    const float* W_raw  = (const float*)d_in[6];
    const float* b_raw  = (const float*)d_in[7];
    const float* W_ps   = (const float*)d_in[8];
    const float* b_ps   = (const float*)d_in[9];
    const float* W_fu   = (const float*)d_in[10];
    const float* b_fu   = (const float*)d_in[11];
    const float* g_raw  = (const float*)d_in[12];
    const float* be_raw = (const float*)d_in[13];
    const float* m_raw  = (const float*)d_in[14];
    const float* v_raw  = (const float*)d_in[15];
    const float* g_ps   = (const float*)d_in[16];
    const float* be_ps  = (const float*)d_in[17];
    const float* m_ps   = (const float*)d_in[18];
    const float* v_ps   = (const float*)d_in[19];
    const float* g_fu   = (const float*)d_in[20];
    const float* be_fu  = (const float*)d_in[21];
    const float* m_fu   = (const float*)d_in[22];
    const float* v_fu   = (const float*)d_in[23];
    float* out = (float*)d_out;

    float*          wsf  = (float*)d_ws;
    unsigned short* wsA1 = (unsigned short*)((char*)d_ws + 4096);
    unsigned short* wsA2 = (unsigned short*)((char*)d_ws + 28672);

    stem_prep<<<41, 64, 0, stream>>>(W_ssig, b_ssig, W_tsig, b_tsig, W_raw, b_raw,
                                     W_ps, b_ps, W_fu, b_fu,
                                     g_raw, be_raw, m_raw, v_raw,
                                     g_ps, be_ps, m_ps, v_ps,
                                     g_fu, be_fu, m_fu, v_fu, wsf, wsA1, wsA2);

    dim3 grid(4, 64, 32);   // (t-chunks, J, B)
    stem_main<<<grid, 64, 0, stream>>>(x, path, wsf, wsA1, wsA2, out);
}